// Round 1
// baseline (234.435 us; speedup 1.0000x reference)
//
#include <hip/hip_runtime.h>
#include <cstdint>
#include <cstddef>

// ---------- types ----------
typedef __attribute__((ext_vector_type(8))) short short8;
typedef __attribute__((ext_vector_type(4))) short short4v;
typedef __attribute__((ext_vector_type(4))) float f32x4;
typedef __attribute__((ext_vector_type(4))) unsigned short ushort4v;
typedef unsigned short ushort_t;

union Frag8 { short4v h[2]; short8 v; };

__device__ __forceinline__ ushort_t f2bf(float f) {
  unsigned int u = __builtin_bit_cast(unsigned int, f);
  u += 0x7FFFu + ((u >> 16) & 1u);   // RNE; inputs finite
  return (ushort_t)(u >> 16);
}

__device__ __forceinline__ void gload16(const void* g, void* l) {
  __builtin_amdgcn_global_load_lds(
      (const __attribute__((address_space(1))) unsigned int*)g,
      (__attribute__((address_space(3))) unsigned int*)l, 16, 0, 0);
}

// ---------- prep kernels ----------
__global__ void cast_x_kernel(const float* __restrict__ x, ushort_t* __restrict__ o) {
  int i = (blockIdx.x * 256 + threadIdx.x) * 4;
  const float4 v = *reinterpret_cast<const float4*>(x + i);
  ushort4v r = { f2bf(v.x), f2bf(v.y), f2bf(v.z), f2bf(v.w) };
  *reinterpret_cast<ushort4v*>(o + i) = r;
}

// Wt[n][k] (bf16, K=1024): rows 0..1023 = Wq^T, 1024..1279 = Wk^T, 1280..1535 = Wv^T,
// 1536..2559 = Wo^T.  Also builds concatenated qkv bias (fp32).
__global__ void prep_w_kernel(const float* __restrict__ Wq, const float* __restrict__ Wk,
                              const float* __restrict__ Wv, const float* __restrict__ Wo,
                              const float* __restrict__ bq, const float* __restrict__ bk,
                              const float* __restrict__ bv,
                              ushort_t* __restrict__ Wt, float* __restrict__ bqkv) {
  int t = blockIdx.x * 256 + threadIdx.x;      // 0 .. 2560*1024-1
  int n = t >> 10, k = t & 1023;
  float v;
  if      (n < 1024) v = Wq[k * 1024 + n];
  else if (n < 1280) v = Wk[k * 256 + (n - 1024)];
  else if (n < 1536) v = Wv[k * 256 + (n - 1280)];
  else               v = Wo[k * 1024 + (n - 1536)];
  Wt[t] = f2bf(v);
  if (t < 1536) bqkv[t] = (t < 1024) ? bq[t] : (t < 1280) ? bk[t - 1024] : bv[t - 1280];
}

// ---------- GEMM: C[M][N] = A[M][K] * Bt[N][K]^T + bias ----------
// 128x128 tile, BK=32, 4 waves (2x2 of 64x64), 16x16x32 bf16 MFMA.
// LDS XOR-swizzle ((row&3) on 16B units) applied on BOTH the global_load_lds
// source address and the ds_read address (both-sides-or-neither rule).
template<bool OUT_BF16>
__global__ __launch_bounds__(256) void gemm_bt_kernel(
    const ushort_t* __restrict__ A, const ushort_t* __restrict__ Bt,
    const float* __restrict__ bias, void* __restrict__ Cout,
    int M, int N, int K)
{
  __shared__ __align__(16) char AsB[8192];
  __shared__ __align__(16) char BsB[8192];
  const int bm = blockIdx.x, bn = blockIdx.y;
  const int tid = threadIdx.x;
  const int w = tid >> 6, lane = tid & 63;
  const int wm = w >> 1, wn = w & 1;
  const int g = lane >> 4, r16 = lane & 15;
  const int lowb = (g & 1) << 3;
  const int u0 = g >> 1;
  const int srow = lane >> 2;      // staging: row within 16-row chunk
  const int pu = lane & 3;         // staging: physical 16B unit within 64B row

  const f32x4 vzero = {0.f, 0.f, 0.f, 0.f};
  f32x4 acc[4][4];
#pragma unroll
  for (int i = 0; i < 4; ++i)
#pragma unroll
    for (int j = 0; j < 4; ++j) acc[i][j] = vzero;

  for (int k0 = 0; k0 < K; k0 += 32) {
#pragma unroll
    for (int c = 0; c < 2; ++c) {
      const int rr = (w * 2 + c) * 16 + srow;
      gload16((const char*)A + ((size_t)(bm * 128 + rr) * K + k0) * 2 + ((pu ^ (rr & 3)) << 4),
              AsB + (w * 2 + c) * 1024);
      gload16((const char*)Bt + ((size_t)(bn * 128 + rr) * K + k0) * 2 + ((pu ^ (rr & 3)) << 4),
              BsB + (w * 2 + c) * 1024);
    }
    __syncthreads();

    Frag8 af[4], bf[4];
#pragma unroll
    for (int mi = 0; mi < 4; ++mi) {
      const int row = wm * 64 + mi * 16 + r16;
      af[mi].h[0] = *(const short4v*)(AsB + row * 64 + ((u0 ^ (row & 3)) << 4) + lowb);
      af[mi].h[1] = *(const short4v*)(AsB + row * 64 + (((2 + u0) ^ (row & 3)) << 4) + lowb);
    }
#pragma unroll
    for (int ni = 0; ni < 4; ++ni) {
      const int row = wn * 64 + ni * 16 + r16;
      bf[ni].h[0] = *(const short4v*)(BsB + row * 64 + ((u0 ^ (row & 3)) << 4) + lowb);
      bf[ni].h[1] = *(const short4v*)(BsB + row * 64 + (((2 + u0) ^ (row & 3)) << 4) + lowb);
    }
#pragma unroll
    for (int mi = 0; mi < 4; ++mi)
#pragma unroll
      for (int ni = 0; ni < 4; ++ni)
        acc[mi][ni] = __builtin_amdgcn_mfma_f32_16x16x32_bf16(af[mi].v, bf[ni].v, acc[mi][ni], 0, 0, 0);
    __syncthreads();
  }

  float bcol[4];
#pragma unroll
  for (int ni = 0; ni < 4; ++ni) bcol[ni] = bias[bn * 128 + wn * 64 + ni * 16 + r16];
#pragma unroll
  for (int mi = 0; mi < 4; ++mi) {
#pragma unroll
    for (int ni = 0; ni < 4; ++ni) {
      const int col = bn * 128 + wn * 64 + ni * 16 + r16;
#pragma unroll
      for (int rr = 0; rr < 4; ++rr) {
        const int row = bm * 128 + wm * 64 + mi * 16 + g * 4 + rr;   // C/D: col=lane&15, row=(lane>>4)*4+reg
        const float val = acc[mi][ni][rr] + bcol[ni];
        if (OUT_BF16) ((ushort_t*)Cout)[(size_t)row * N + col] = f2bf(val);
        else          ((float*)Cout)[(size_t)row * N + col] = val;
      }
    }
  }
}

// ---------- attention ----------
// qkv row-major [8192][1536] bf16: cols 0..1023 Q (h*64+d), 1024..1279 K (g*64+d), 1280..1535 V.
// Block = (qtile of 64 queries, head, batch); 4 waves x 16 queries.
// Swapped QK^T: S^T = K_tile * Q^T so P's C-layout == PV's A-fragment layout.
__global__ __launch_bounds__(256) void attn_kernel(
    const ushort_t* __restrict__ qkv, ushort_t* __restrict__ attout)
{
  __shared__ __align__(16) char KsB[4096];   // K tile [32 keys][64 d], 128B rows, XOR-swz (key&7)
  __shared__ __align__(16) char VtB[4096];   // V^T tile [64 d][32 keys], 64B rows, XOR-swz (d&3)
  const int qt = blockIdx.x, h = blockIdx.y, b = blockIdx.z;
  const int gg = h >> 2;                     // KV group
  const int tid = threadIdx.x;
  const int w = tid >> 6, lane = tid & 63;
  const int g = lane >> 4, r16 = lane & 15;
  const int lowb = (g & 1) << 3;
  const int u0 = g >> 1;

  // Q fragments (registers; used as MFMA B operand). d = dc*32 + hh*16 + 4*g + j
  Frag8 qf[2];
  {
    const int qrow = b * 2048 + qt * 64 + w * 16 + r16;
    const char* qptr = (const char*)qkv + (size_t)qrow * 3072 + h * 128;
#pragma unroll
    for (int dc = 0; dc < 2; ++dc)
#pragma unroll
      for (int hh = 0; hh < 2; ++hh)
        qf[dc].h[hh] = *(const short4v*)(qptr + dc * 64 + hh * 32 + g * 8);
  }

  const f32x4 vzero = {0.f, 0.f, 0.f, 0.f};
  f32x4 accO[4];
#pragma unroll
  for (int i = 0; i < 4; ++i) accO[i] = vzero;
  float mrun = -1e30f, lsum = 0.f;
  const int q_global = qt * 64 + w * 16 + r16;
  const int kend = qt * 64 + 64;
  int kb0 = qt * 64 - 511; if (kb0 < 0) kb0 = 0; kb0 &= ~31;

  for (int kb = kb0; kb < kend; kb += 32) {
    { // stage K via gload_lds, source pre-swizzled
      const int rr = w * 8 + (lane >> 3);
      const int pk = lane & 7;
      gload16((const char*)qkv + (size_t)(b * 2048 + kb + rr) * 3072 + 2048 + gg * 128
                  + ((pk ^ (rr & 7)) << 4),
              KsB + w * 1024);
    }
    { // stage V transposed (reg-staged, swizzled ds writes)
      const int kk = tid >> 3;
      const int d0 = (tid & 7) * 8;
      const short8 vv = *(const short8*)((const char*)qkv
          + (size_t)(b * 2048 + kb + kk) * 3072 + 2560 + gg * 128 + d0 * 2);
#pragma unroll
      for (int i = 0; i < 8; ++i) {
        const int d = d0 + i;
        const int off = d * 64 + (((kk >> 3) ^ (d & 3)) << 4) + (kk & 7) * 2;
        *(ushort_t*)(VtB + off) = (ushort_t)vv[i];
      }
    }
    __syncthreads();

    // K fragments: A operand, m = key (l&15), k = d
    Frag8 kf[2][2];
#pragma unroll
    for (int ki = 0; ki < 2; ++ki) {
      const int key = ki * 16 + r16;
#pragma unroll
      for (int dc = 0; dc < 2; ++dc)
#pragma unroll
        for (int hh = 0; hh < 2; ++hh) {
          const int unit = dc * 4 + hh * 2 + u0;
          kf[ki][dc].h[hh] = *(const short4v*)(KsB + key * 128 + ((unit ^ (key & 7)) << 4) + lowb);
        }
    }
    f32x4 st[2];
    st[0] = __builtin_amdgcn_mfma_f32_16x16x32_bf16(kf[0][0].v, qf[0].v, vzero, 0, 0, 0);
    st[0] = __builtin_amdgcn_mfma_f32_16x16x32_bf16(kf[0][1].v, qf[1].v, st[0], 0, 0, 0);
    st[1] = __builtin_amdgcn_mfma_f32_16x16x32_bf16(kf[1][0].v, qf[0].v, vzero, 0, 0, 0);
    st[1] = __builtin_amdgcn_mfma_f32_16x16x32_bf16(kf[1][1].v, qf[1].v, st[1], 0, 0, 0);

    // scale + sliding-window causal mask. S^T: row=key ((l>>4)*4+r), col=query (l&15)
    float p[2][4];
    float tm = -INFINITY;
#pragma unroll
    for (int ki = 0; ki < 2; ++ki)
#pragma unroll
      for (int r = 0; r < 4; ++r) {
        const int key = kb + ki * 16 + g * 4 + r;
        float s = st[ki][r] * 0.125f;
        const bool valid = (key <= q_global) && (key + 512 > q_global);
        s = valid ? s : -INFINITY;
        p[ki][r] = s;
        tm = fmaxf(tm, s);
      }
    tm = fmaxf(tm, __shfl_xor(tm, 16));
    tm = fmaxf(tm, __shfl_xor(tm, 32));
    const float mnew = fmaxf(mrun, tm);
    const float corr = exp2f((mrun - mnew) * 1.44269504f);
    float tsum = 0.f;
#pragma unroll
    for (int ki = 0; ki < 2; ++ki)
#pragma unroll
      for (int r = 0; r < 4; ++r) {
        const float e = exp2f((p[ki][r] - mnew) * 1.44269504f);
        p[ki][r] = e;
        tsum += e;
      }
    tsum += __shfl_xor(tsum, 16);
    tsum += __shfl_xor(tsum, 32);
    lsum = lsum * corr + tsum;
    mrun = mnew;

    // rescale O (stats live at query=lane&15; O rows are query=4*g+rr)
    float cq[4];
#pragma unroll
    for (int rr = 0; rr < 4; ++rr) cq[rr] = __shfl(corr, g * 4 + rr);
#pragma unroll
    for (int nt = 0; nt < 4; ++nt)
#pragma unroll
      for (int rr = 0; rr < 4; ++rr) accO[nt][rr] *= cq[rr];

    // P fragment: A operand element j -> k = 16*(j>>2) + 4*g + (j&3)  == S^T C-layout
    Frag8 pf;
#pragma unroll
    for (int j = 0; j < 4; ++j) {
      pf.v[j]     = (short)f2bf(p[0][j]);
      pf.v[4 + j] = (short)f2bf(p[1][j]);
    }
    // PV: B operand from V^T LDS; n = d (nt*16 + l&15), k = key
#pragma unroll
    for (int nt = 0; nt < 4; ++nt) {
      const int d = nt * 16 + r16;
      Frag8 vf;
#pragma unroll
      for (int hh = 0; hh < 2; ++hh) {
        const int unit = hh * 2 + u0;
        vf.h[hh] = *(const short4v*)(VtB + d * 64 + ((unit ^ (d & 3)) << 4) + lowb);
      }
      accO[nt] = __builtin_amdgcn_mfma_f32_16x16x32_bf16(pf.v, vf.v, accO[nt], 0, 0, 0);
    }
    __syncthreads();
  }

  const float linv = 1.f / lsum;
  float lq[4];
#pragma unroll
  for (int rr = 0; rr < 4; ++rr) lq[rr] = __shfl(linv, g * 4 + rr);
#pragma unroll
  for (int nt = 0; nt < 4; ++nt) {
    const int ocol = h * 64 + nt * 16 + r16;
#pragma unroll
    for (int rr = 0; rr < 4; ++rr) {
      const int orow = b * 2048 + qt * 64 + w * 16 + g * 4 + rr;
      attout[(size_t)orow * 1024 + ocol] = f2bf(accO[nt][rr] * lq[rr]);
    }
  }
}

// ---------- launch ----------
extern "C" void kernel_launch(void* const* d_in, const int* in_sizes, int n_in,
                              void* d_out, int out_size, void* d_ws, size_t ws_size,
                              hipStream_t stream) {
  (void)in_sizes; (void)n_in; (void)out_size; (void)ws_size;
  const float* x  = (const float*)d_in[0];
  const float* Wq = (const float*)d_in[1];
  const float* bq = (const float*)d_in[2];
  const float* Wk = (const float*)d_in[3];
  const float* bk = (const float*)d_in[4];
  const float* Wv = (const float*)d_in[5];
  const float* bv = (const float*)d_in[6];
  const float* Wo = (const float*)d_in[7];
  const float* bo = (const float*)d_in[8];

  char* ws = (char*)d_ws;
  ushort_t* xb   = (ushort_t*)(ws + 0);          // 8192*1024 bf16   = 16 MiB
  ushort_t* wt   = (ushort_t*)(ws + 16777216);   // 2560*1024 bf16   = 5 MiB
  float*    bqkv = (float*)   (ws + 22020096);   // 1536 fp32
  ushort_t* qkv  = (ushort_t*)(ws + 22028288);   // 8192*1536 bf16   = 24 MiB
  ushort_t* att  = (ushort_t*)(ws + 47194112);   // 8192*1024 bf16   = 16 MiB

  cast_x_kernel<<<8192, 256, 0, stream>>>(x, xb);
  prep_w_kernel<<<10240, 256, 0, stream>>>(Wq, Wk, Wv, Wo, bq, bk, bv, wt, bqkv);
  gemm_bt_kernel<true><<<dim3(64, 12), 256, 0, stream>>>(xb, wt, bqkv, qkv, 8192, 1536, 1024);
  attn_kernel<<<dim3(32, 16, 4), 256, 0, stream>>>(qkv, att);
  gemm_bt_kernel<false><<<dim3(64, 8), 256, 0, stream>>>(att, wt + (size_t)1536 * 1024, bo,
                                                         (float*)d_out, 8192, 1024, 1024);
}

// Round 2
// 199.177 us; speedup vs baseline: 1.1770x; 1.1770x over previous
//
#include <hip/hip_runtime.h>
#include <cstdint>
#include <cstddef>

// ---------- types ----------
typedef __attribute__((ext_vector_type(8))) short short8;
typedef __attribute__((ext_vector_type(4))) short short4v;
typedef __attribute__((ext_vector_type(4))) float f32x4;
typedef __attribute__((ext_vector_type(4))) unsigned short ushort4v;
typedef unsigned short ushort_t;

union Frag8 { short4v h[2]; short8 v; };

__device__ __forceinline__ ushort_t f2bf(float f) {
  unsigned int u = __builtin_bit_cast(unsigned int, f);
  u += 0x7FFFu + ((u >> 16) & 1u);   // RNE; inputs finite
  return (ushort_t)(u >> 16);
}

__device__ __forceinline__ void gload16(const void* g, void* l) {
  __builtin_amdgcn_global_load_lds(
      (const __attribute__((address_space(1))) unsigned int*)g,
      (__attribute__((address_space(3))) unsigned int*)l, 16, 0, 0);
}

// ---------- prep kernels ----------
__global__ void cast_x_kernel(const float* __restrict__ x, ushort_t* __restrict__ o) {
  int i = (blockIdx.x * 256 + threadIdx.x) * 4;
  const float4 v = *reinterpret_cast<const float4*>(x + i);
  ushort4v r = { f2bf(v.x), f2bf(v.y), f2bf(v.z), f2bf(v.w) };
  *reinterpret_cast<ushort4v*>(o + i) = r;
}

// Tiled transpose: W[k][n] fp32 -> Wt[n][k] bf16.  Wt rows: 0..1023 Wq^T,
// 1024..1279 Wk^T, 1280..1535 Wv^T, 1536..2559 Wo^T.
__global__ __launch_bounds__(256) void transpose_w_kernel(
    const float* __restrict__ Wq, const float* __restrict__ Wk,
    const float* __restrict__ Wv, const float* __restrict__ Wo,
    ushort_t* __restrict__ Wt) {
  __shared__ float tile[32][33];
  const int tn = blockIdx.x, tk = blockIdx.y;
  const int n0 = tn * 32;
  const float* W; int ldn, nloc;
  if      (n0 < 1024) { W = Wq; ldn = 1024; nloc = n0; }
  else if (n0 < 1280) { W = Wk; ldn = 256;  nloc = n0 - 1024; }
  else if (n0 < 1536) { W = Wv; ldn = 256;  nloc = n0 - 1280; }
  else                { W = Wo; ldn = 1024; nloc = n0 - 1536; }
  const int t = threadIdx.x;
  const int sr = t >> 3, sc = (t & 7) * 4;
  const float4 v = *reinterpret_cast<const float4*>(W + (size_t)(tk * 32 + sr) * ldn + nloc + sc);
  tile[sr][sc] = v.x; tile[sr][sc + 1] = v.y; tile[sr][sc + 2] = v.z; tile[sr][sc + 3] = v.w;
  __syncthreads();
  const int wr = t >> 3, wc = (t & 7) * 4;
  ushort4v o = { f2bf(tile[wc][wr]), f2bf(tile[wc + 1][wr]),
                 f2bf(tile[wc + 2][wr]), f2bf(tile[wc + 3][wr]) };
  *reinterpret_cast<ushort4v*>(Wt + (size_t)(n0 + wr) * 1024 + tk * 32 + wc) = o;
}

__global__ void prep_bias_kernel(const float* __restrict__ bq, const float* __restrict__ bk,
                                 const float* __restrict__ bv, float* __restrict__ bqkv) {
  int t = blockIdx.x * 256 + threadIdx.x;
  if (t < 1536) bqkv[t] = (t < 1024) ? bq[t] : (t < 1280) ? bk[t - 1024] : bv[t - 1280];
}

// ---------- GEMM core macro-ish: 128x128 tile, BK=32, 4 waves, 16x16x32 bf16 ----------
// QKV GEMM: writes Qb [8192][1024], Kb [b*4+g][2048][64], Vt [b*4+g][64][2048] (all bf16)
__global__ __launch_bounds__(256) void gemm_qkv_kernel(
    const ushort_t* __restrict__ A, const ushort_t* __restrict__ Bt,
    const float* __restrict__ bias,
    ushort_t* __restrict__ Qb, ushort_t* __restrict__ Kb, ushort_t* __restrict__ Vt)
{
  const int K = 1024;
  __shared__ __align__(16) char AsB[8192];
  __shared__ __align__(16) char BsB[8192];
  const int bm = blockIdx.x, bn = blockIdx.y;
  const int tid = threadIdx.x;
  const int w = tid >> 6, lane = tid & 63;
  const int wm = w >> 1, wn = w & 1;
  const int g = lane >> 4, r16 = lane & 15;
  const int lowb = (g & 1) << 3;
  const int u0 = g >> 1;
  const int srow = lane >> 2;
  const int pu = lane & 3;

  const f32x4 vzero = {0.f, 0.f, 0.f, 0.f};
  f32x4 acc[4][4];
#pragma unroll
  for (int i = 0; i < 4; ++i)
#pragma unroll
    for (int j = 0; j < 4; ++j) acc[i][j] = vzero;

  for (int k0 = 0; k0 < K; k0 += 32) {
#pragma unroll
    for (int c = 0; c < 2; ++c) {
      const int rr = (w * 2 + c) * 16 + srow;
      gload16((const char*)A + ((size_t)(bm * 128 + rr) * K + k0) * 2 + ((pu ^ (rr & 3)) << 4),
              AsB + (w * 2 + c) * 1024);
      gload16((const char*)Bt + ((size_t)(bn * 128 + rr) * K + k0) * 2 + ((pu ^ (rr & 3)) << 4),
              BsB + (w * 2 + c) * 1024);
    }
    __syncthreads();
    Frag8 af[4], bf[4];
#pragma unroll
    for (int mi = 0; mi < 4; ++mi) {
      const int row = wm * 64 + mi * 16 + r16;
      af[mi].h[0] = *(const short4v*)(AsB + row * 64 + ((u0 ^ (row & 3)) << 4) + lowb);
      af[mi].h[1] = *(const short4v*)(AsB + row * 64 + (((2 + u0) ^ (row & 3)) << 4) + lowb);
    }
#pragma unroll
    for (int ni = 0; ni < 4; ++ni) {
      const int row = wn * 64 + ni * 16 + r16;
      bf[ni].h[0] = *(const short4v*)(BsB + row * 64 + ((u0 ^ (row & 3)) << 4) + lowb);
      bf[ni].h[1] = *(const short4v*)(BsB + row * 64 + (((2 + u0) ^ (row & 3)) << 4) + lowb);
    }
#pragma unroll
    for (int mi = 0; mi < 4; ++mi)
#pragma unroll
      for (int ni = 0; ni < 4; ++ni)
        acc[mi][ni] = __builtin_amdgcn_mfma_f32_16x16x32_bf16(af[mi].v, bf[ni].v, acc[mi][ni], 0, 0, 0);
    __syncthreads();
  }

  float bcol[4];
#pragma unroll
  for (int ni = 0; ni < 4; ++ni) bcol[ni] = bias[bn * 128 + wn * 64 + ni * 16 + r16];
  const int bb = bm >> 4;                    // batch (128 | 2048)
  if (bn < 8) {                              // ---- Q ----
#pragma unroll
    for (int mi = 0; mi < 4; ++mi)
#pragma unroll
      for (int ni = 0; ni < 4; ++ni) {
        const int col = bn * 128 + wn * 64 + ni * 16 + r16;
#pragma unroll
        for (int rr = 0; rr < 4; ++rr) {
          const int row = bm * 128 + wm * 64 + mi * 16 + g * 4 + rr;
          Qb[(size_t)row * 1024 + col] = f2bf(acc[mi][ni][rr] + bcol[ni]);
        }
      }
  } else if (bn < 10) {                      // ---- K ----
#pragma unroll
    for (int mi = 0; mi < 4; ++mi)
#pragma unroll
      for (int ni = 0; ni < 4; ++ni) {
        const int c = bn * 128 + wn * 64 + ni * 16 + r16 - 1024;
        const int gi = c >> 6, dd = c & 63;
#pragma unroll
        for (int rr = 0; rr < 4; ++rr) {
          const int row = bm * 128 + wm * 64 + mi * 16 + g * 4 + rr;
          const int s = row & 2047;
          Kb[((size_t)(bb * 4 + gi) * 2048 + s) * 64 + dd] = f2bf(acc[mi][ni][rr] + bcol[ni]);
        }
      }
  } else {                                   // ---- V -> transposed ----
#pragma unroll
    for (int mi = 0; mi < 4; ++mi) {
      const int s0 = (bm * 128 + wm * 64 + mi * 16 + g * 4) & 2047;
#pragma unroll
      for (int ni = 0; ni < 4; ++ni) {
        const int c = bn * 128 + wn * 64 + ni * 16 + r16 - 1280;
        const int gi = c >> 6, dd = c & 63;
        ushort4v pk;
#pragma unroll
        for (int rr = 0; rr < 4; ++rr) pk[rr] = f2bf(acc[mi][ni][rr] + bcol[ni]);
        *reinterpret_cast<ushort4v*>(Vt + ((size_t)(bb * 4 + gi) * 64 + dd) * 2048 + s0) = pk;
      }
    }
  }
}

// Output GEMM: C[M][N] fp32 = A * Bt^T + bias
__global__ __launch_bounds__(256) void gemm_bt_kernel(
    const ushort_t* __restrict__ A, const ushort_t* __restrict__ Bt,
    const float* __restrict__ bias, float* __restrict__ Cout,
    int M, int N, int K)
{
  __shared__ __align__(16) char AsB[8192];
  __shared__ __align__(16) char BsB[8192];
  const int bm = blockIdx.x, bn = blockIdx.y;
  const int tid = threadIdx.x;
  const int w = tid >> 6, lane = tid & 63;
  const int wm = w >> 1, wn = w & 1;
  const int g = lane >> 4, r16 = lane & 15;
  const int lowb = (g & 1) << 3;
  const int u0 = g >> 1;
  const int srow = lane >> 2;
  const int pu = lane & 3;

  const f32x4 vzero = {0.f, 0.f, 0.f, 0.f};
  f32x4 acc[4][4];
#pragma unroll
  for (int i = 0; i < 4; ++i)
#pragma unroll
    for (int j = 0; j < 4; ++j) acc[i][j] = vzero;

  for (int k0 = 0; k0 < K; k0 += 32) {
#pragma unroll
    for (int c = 0; c < 2; ++c) {
      const int rr = (w * 2 + c) * 16 + srow;
      gload16((const char*)A + ((size_t)(bm * 128 + rr) * K + k0) * 2 + ((pu ^ (rr & 3)) << 4),
              AsB + (w * 2 + c) * 1024);
      gload16((const char*)Bt + ((size_t)(bn * 128 + rr) * K + k0) * 2 + ((pu ^ (rr & 3)) << 4),
              BsB + (w * 2 + c) * 1024);
    }
    __syncthreads();
    Frag8 af[4], bf[4];
#pragma unroll
    for (int mi = 0; mi < 4; ++mi) {
      const int row = wm * 64 + mi * 16 + r16;
      af[mi].h[0] = *(const short4v*)(AsB + row * 64 + ((u0 ^ (row & 3)) << 4) + lowb);
      af[mi].h[1] = *(const short4v*)(AsB + row * 64 + (((2 + u0) ^ (row & 3)) << 4) + lowb);
    }
#pragma unroll
    for (int ni = 0; ni < 4; ++ni) {
      const int row = wn * 64 + ni * 16 + r16;
      bf[ni].h[0] = *(const short4v*)(BsB + row * 64 + ((u0 ^ (row & 3)) << 4) + lowb);
      bf[ni].h[1] = *(const short4v*)(BsB + row * 64 + (((2 + u0) ^ (row & 3)) << 4) + lowb);
    }
#pragma unroll
    for (int mi = 0; mi < 4; ++mi)
#pragma unroll
      for (int ni = 0; ni < 4; ++ni)
        acc[mi][ni] = __builtin_amdgcn_mfma_f32_16x16x32_bf16(af[mi].v, bf[ni].v, acc[mi][ni], 0, 0, 0);
    __syncthreads();
  }

  float bcol[4];
#pragma unroll
  for (int ni = 0; ni < 4; ++ni) bcol[ni] = bias[bn * 128 + wn * 64 + ni * 16 + r16];
#pragma unroll
  for (int mi = 0; mi < 4; ++mi)
#pragma unroll
    for (int ni = 0; ni < 4; ++ni) {
      const int col = bn * 128 + wn * 64 + ni * 16 + r16;
#pragma unroll
      for (int rr = 0; rr < 4; ++rr) {
        const int row = bm * 128 + wm * 64 + mi * 16 + g * 4 + rr;
        Cout[(size_t)row * N + col] = acc[mi][ni][rr] + bcol[ni];
      }
    }
}

// ---------- attention ----------
// Block = (qtile 64, group, batch) via XCD-swizzled flat id; 8 waves:
// w = qh*4 + head-in-group... (hw = w&3 head, qh = w>>2 query half of 32).
// K/V staged ONCE per block (shared by 4 heads), double-buffered, 1 barrier/tile.
// Swapped QK^T (S^T = K*Q^T) so P's C-layout feeds PV's A operand in-register.
__global__ __launch_bounds__(512, 4) void attn_kernel(
    const ushort_t* __restrict__ Qb, const ushort_t* __restrict__ Kb,
    const ushort_t* __restrict__ Vt, ushort_t* __restrict__ attout)
{
  __shared__ __align__(16) char KsB[8192];   // 2 x [32 keys][128B], XOR-swz (key&7)
  __shared__ __align__(16) char VsB[8192];   // 2 x [64 d][64B],     XOR-swz (d&3)
  // XCD swizzle: each XCD gets 4 consecutive qt for all 16 (g,b) pairs.
  const int fid = blockIdx.x + 32 * (blockIdx.y + 4 * blockIdx.z);
  const int j = fid >> 3;
  const int qt = (fid & 7) * 4 + (j >> 4);
  const int gg = j & 3, b = (j >> 2) & 3;

  const int tid = threadIdx.x;
  const int w = tid >> 6, lane = tid & 63;
  const int hw = w & 3, qh = w >> 2;
  const int h = gg * 4 + hw;
  const int g = lane >> 4, r16 = lane & 15;
  const int u0 = g >> 1;
  const int lowb = (g & 1) << 3;
  const int q0w = qt * 64 + qh * 32;

  // Q fragments: 2 q-subtiles x 2 k-chunks (k = d)
  Frag8 qf[2][2];
#pragma unroll
  for (int qs = 0; qs < 2; ++qs) {
    const char* qptr = (const char*)Qb + ((size_t)(b * 2048 + q0w + qs * 16 + r16) * 1024 + h * 64) * 2;
#pragma unroll
    for (int dc = 0; dc < 2; ++dc)
#pragma unroll
      for (int hh = 0; hh < 2; ++hh)
        qf[qs][dc].h[hh] = *(const short4v*)(qptr + dc * 64 + hh * 32 + g * 8);
  }

  const f32x4 vzero = {0.f, 0.f, 0.f, 0.f};
  f32x4 accO[2][4];
#pragma unroll
  for (int qs = 0; qs < 2; ++qs)
#pragma unroll
    for (int nt = 0; nt < 4; ++nt) accO[qs][nt] = vzero;
  float mrun[2] = {-1e30f, -1e30f};
  float lsum[2] = {0.f, 0.f};

  const char* KbB = (const char*)Kb + (size_t)(b * 4 + gg) * 2048 * 128;  // key rows 128B
  const char* VtB = (const char*)Vt + (size_t)(b * 4 + gg) * 2048 * 128;  // d rows 4096B

  const int kb0 = (qt >= 8) ? (qt * 64 - 512) : 0;
  const int kend = qt * 64 + 64;

  auto stage = [&](int buf, int kb) {
    if (tid < 256) {
      const int rr = tid >> 3, pk = tid & 7;
      gload16(KbB + (size_t)(kb + rr) * 128 + ((pk ^ (rr & 7)) << 4),
              KsB + buf * 4096 + w * 1024);
    } else {
      const int u = tid - 256;
      const int d = u >> 2, pv = u & 3;
      gload16(VtB + (size_t)d * 4096 + kb * 2 + ((pv ^ (d & 3)) << 4),
              VsB + buf * 4096 + (w - 4) * 1024);
    }
  };

  stage(0, kb0);
  __syncthreads();
  int cur = 0;
  for (int kb = kb0; kb < kend; kb += 32) {
    if (kb + 32 < kend) stage(cur ^ 1, kb + 32);
    const bool active = (kb >= q0w - 512) && (kb <= q0w);
    if (active) {
      const char* Ks = KsB + cur * 4096;
      const char* Vs = VsB + cur * 4096;
      const bool full = (kb >= q0w - 480) && (kb <= q0w - 32);

      f32x4 st[2][2];
#pragma unroll
      for (int ki = 0; ki < 2; ++ki) {
        const int key = ki * 16 + r16;
        const int swz = key & 7;
        Frag8 kf0, kf1;
        kf0.h[0] = *(const short4v*)(Ks + key * 128 + (((0 + u0) ^ swz) << 4) + lowb);
        kf0.h[1] = *(const short4v*)(Ks + key * 128 + (((2 + u0) ^ swz) << 4) + lowb);
        kf1.h[0] = *(const short4v*)(Ks + key * 128 + (((4 + u0) ^ swz) << 4) + lowb);
        kf1.h[1] = *(const short4v*)(Ks + key * 128 + (((6 + u0) ^ swz) << 4) + lowb);
#pragma unroll
        for (int qs = 0; qs < 2; ++qs) {
          st[qs][ki] = __builtin_amdgcn_mfma_f32_16x16x32_bf16(kf0.v, qf[qs][0].v, vzero, 0, 0, 0);
          st[qs][ki] = __builtin_amdgcn_mfma_f32_16x16x32_bf16(kf1.v, qf[qs][1].v, st[qs][ki], 0, 0, 0);
        }
      }

      Frag8 pf[2];
#pragma unroll
      for (int qs = 0; qs < 2; ++qs) {
        float pr[8];
        float tm = -INFINITY;
#pragma unroll
        for (int ki = 0; ki < 2; ++ki)
#pragma unroll
          for (int r = 0; r < 4; ++r) {
            float s = st[qs][ki][r] * 0.180336881f;   // (1/8)*log2(e) -> log2 domain
            if (!full) {
              const int key = kb + ki * 16 + g * 4 + r;
              const int q = q0w + qs * 16 + r16;
              const bool valid = (key <= q) && (key + 512 > q);
              s = valid ? s : -INFINITY;
            }
            pr[ki * 4 + r] = s;
            tm = fmaxf(tm, s);
          }
        tm = fmaxf(tm, __shfl_xor(tm, 16));
        tm = fmaxf(tm, __shfl_xor(tm, 32));
        const float mnew = fmaxf(mrun[qs], tm);
        const float corr = exp2f(mrun[qs] - mnew);
        float tsum = 0.f;
#pragma unroll
        for (int i = 0; i < 8; ++i) {
          const float e = exp2f(pr[i] - mnew);
          pr[i] = e;
          tsum += e;
        }
        tsum += __shfl_xor(tsum, 16);
        tsum += __shfl_xor(tsum, 32);
        lsum[qs] = lsum[qs] * corr + tsum;
        mrun[qs] = mnew;
        float cq[4];
#pragma unroll
        for (int rr = 0; rr < 4; ++rr) cq[rr] = __shfl(corr, g * 4 + rr);
#pragma unroll
        for (int nt = 0; nt < 4; ++nt)
#pragma unroll
          for (int rr = 0; rr < 4; ++rr) accO[qs][nt][rr] *= cq[rr];
#pragma unroll
        for (int jj = 0; jj < 4; ++jj) {
          pf[qs].v[jj]     = (short)f2bf(pr[jj]);
          pf[qs].v[4 + jj] = (short)f2bf(pr[4 + jj]);
        }
      }

#pragma unroll
      for (int nt = 0; nt < 4; ++nt) {
        const int d = nt * 16 + r16;
        Frag8 vf;
        vf.h[0] = *(const short4v*)(Vs + d * 64 + (((0 + u0) ^ (d & 3)) << 4) + lowb);
        vf.h[1] = *(const short4v*)(Vs + d * 64 + (((2 + u0) ^ (d & 3)) << 4) + lowb);
#pragma unroll
        for (int qs = 0; qs < 2; ++qs)
          accO[qs][nt] = __builtin_amdgcn_mfma_f32_16x16x32_bf16(pf[qs].v, vf.v, accO[qs][nt], 0, 0, 0);
      }
    }
    __syncthreads();
    cur ^= 1;
  }

#pragma unroll
  for (int qs = 0; qs < 2; ++qs) {
    const float linv = 1.f / lsum[qs];
    float lq[4];
#pragma unroll
    for (int rr = 0; rr < 4; ++rr) lq[rr] = __shfl(linv, g * 4 + rr);
#pragma unroll
    for (int nt = 0; nt < 4; ++nt) {
      const int ocol = h * 64 + nt * 16 + r16;
#pragma unroll
      for (int rr = 0; rr < 4; ++rr) {
        const int orow = b * 2048 + q0w + qs * 16 + g * 4 + rr;
        attout[(size_t)orow * 1024 + ocol] = f2bf(accO[qs][nt][rr] * lq[rr]);
      }
    }
  }
}

// ---------- launch ----------
extern "C" void kernel_launch(void* const* d_in, const int* in_sizes, int n_in,
                              void* d_out, int out_size, void* d_ws, size_t ws_size,
                              hipStream_t stream) {
  (void)in_sizes; (void)n_in; (void)out_size; (void)ws_size;
  const float* x  = (const float*)d_in[0];
  const float* Wq = (const float*)d_in[1];
  const float* bq = (const float*)d_in[2];
  const float* Wk = (const float*)d_in[3];
  const float* bk = (const float*)d_in[4];
  const float* Wv = (const float*)d_in[5];
  const float* bv = (const float*)d_in[6];
  const float* Wo = (const float*)d_in[7];
  const float* bo = (const float*)d_in[8];

  char* ws = (char*)d_ws;
  ushort_t* Qb   = (ushort_t*)(ws + 0);          // 8192x1024 bf16 = 16 MiB
  ushort_t* Kb   = (ushort_t*)(ws + 16777216);   // 16x2048x64 bf16 = 4 MiB
  ushort_t* Vt   = (ushort_t*)(ws + 20971520);   // 16x64x2048 bf16 = 4 MiB
  ushort_t* wt   = (ushort_t*)(ws + 25165824);   // 2560x1024 bf16 = 5 MiB
  float*    bqkv = (float*)   (ws + 30408704);   // 1536 fp32
  ushort_t* xb   = (ushort_t*)(ws + 30416896);   // 8192x1024 bf16 = 16 MiB
  ushort_t* att  = (ushort_t*)(ws + 47194112);   // 8192x1024 bf16 = 16 MiB

  cast_x_kernel<<<8192, 256, 0, stream>>>(x, xb);
  transpose_w_kernel<<<dim3(80, 32), 256, 0, stream>>>(Wq, Wk, Wv, Wo, wt);
  prep_bias_kernel<<<6, 256, 0, stream>>>(bq, bk, bv, bqkv);
  gemm_qkv_kernel<<<dim3(64, 12), 256, 0, stream>>>(xb, wt, bqkv, Qb, Kb, Vt);
  attn_kernel<<<dim3(32, 4, 4), 512, 0, stream>>>(Qb, Kb, Vt, att);
  gemm_bt_kernel<<<dim3(64, 8), 256, 0, stream>>>(att, wt + (size_t)1536 * 1024, bo,
                                                  (float*)d_out, 8192, 1024, 1024);
}

// Round 3
// 136.611 us; speedup vs baseline: 1.7161x; 1.4580x over previous
//
#include <hip/hip_runtime.h>
#include <cstdint>
#include <cstddef>

// ---------- types ----------
typedef __attribute__((ext_vector_type(8))) short short8;
typedef __attribute__((ext_vector_type(4))) short short4v;
typedef __attribute__((ext_vector_type(4))) float f32x4;
typedef __attribute__((ext_vector_type(4))) unsigned short ushort4v;
typedef unsigned short ushort_t;

union Frag8 { short4v h[2]; short8 v; };

__device__ __forceinline__ ushort_t f2bf(float f) {
  unsigned int u = __builtin_bit_cast(unsigned int, f);
  u += 0x7FFFu + ((u >> 16) & 1u);   // RNE; inputs finite
  return (ushort_t)(u >> 16);
}

__device__ __forceinline__ void gload16(const void* g, void* l) {
  __builtin_amdgcn_global_load_lds(
      (const __attribute__((address_space(1))) unsigned int*)g,
      (__attribute__((address_space(3))) unsigned int*)l, 16, 0, 0);
}

// ---------- prep kernels ----------
__global__ void cast_x_kernel(const float* __restrict__ x, ushort_t* __restrict__ o) {
  int i = (blockIdx.x * 256 + threadIdx.x) * 4;
  const float4 v = *reinterpret_cast<const float4*>(x + i);
  ushort4v r = { f2bf(v.x), f2bf(v.y), f2bf(v.z), f2bf(v.w) };
  *reinterpret_cast<ushort4v*>(o + i) = r;
}

// Tiled transpose: W[k][n] fp32 -> Wt[n][k] bf16.  Wt rows: 0..1023 Wq^T,
// 1024..1279 Wk^T, 1280..1535 Wv^T, 1536..2559 Wo^T.
__global__ __launch_bounds__(256) void transpose_w_kernel(
    const float* __restrict__ Wq, const float* __restrict__ Wk,
    const float* __restrict__ Wv, const float* __restrict__ Wo,
    ushort_t* __restrict__ Wt) {
  __shared__ float tile[32][33];
  const int tn = blockIdx.x, tk = blockIdx.y;
  const int n0 = tn * 32;
  const float* W; int ldn, nloc;
  if      (n0 < 1024) { W = Wq; ldn = 1024; nloc = n0; }
  else if (n0 < 1280) { W = Wk; ldn = 256;  nloc = n0 - 1024; }
  else if (n0 < 1536) { W = Wv; ldn = 256;  nloc = n0 - 1280; }
  else                { W = Wo; ldn = 1024; nloc = n0 - 1536; }
  const int t = threadIdx.x;
  const int sr = t >> 3, sc = (t & 7) * 4;
  const float4 v = *reinterpret_cast<const float4*>(W + (size_t)(tk * 32 + sr) * ldn + nloc + sc);
  tile[sr][sc] = v.x; tile[sr][sc + 1] = v.y; tile[sr][sc + 2] = v.z; tile[sr][sc + 3] = v.w;
  __syncthreads();
  const int wr = t >> 3, wc = (t & 7) * 4;
  ushort4v o = { f2bf(tile[wc][wr]), f2bf(tile[wc + 1][wr]),
                 f2bf(tile[wc + 2][wr]), f2bf(tile[wc + 3][wr]) };
  *reinterpret_cast<ushort4v*>(Wt + (size_t)(n0 + wr) * 1024 + tk * 32 + wc) = o;
}

__global__ void prep_bias_kernel(const float* __restrict__ bq, const float* __restrict__ bk,
                                 const float* __restrict__ bv, float* __restrict__ bqkv) {
  int t = blockIdx.x * 256 + threadIdx.x;
  if (t < 1536) bqkv[t] = (t < 1024) ? bq[t] : (t < 1280) ? bk[t - 1024] : bv[t - 1280];
}

// ---------- GEMM core (shared by both GEMMs via macro-free duplication) ----------
// 128x128 tile, BK=64 (128B LDS rows), 4 waves (2x2 of 64x64), 16x16x32 bf16 MFMA.
// Fragments: consistent-kappa contiguous 16B per lane -> single ds_read_b128.
// LDS 16B-unit swizzle U' = U ^ (row&7): conflict-free (8 consecutive lanes span
// all 32 banks).  Staging: linear LDS dest, pre-swizzled global source (rule 21).
// Double-buffered: stage(t+1) issued BEFORE compute(t); one vmcnt-drain barrier/iter.
//
// GEMM_CORE defines: acc[4][4] after K loop; uses bm, bn, tid-derived ids.
#define GEMM_IDS \
  const int tid = threadIdx.x;                        \
  const int w = tid >> 6, lane = tid & 63;            \
  const int wm = w >> 1, wn = w & 1;                  \
  const int g = lane >> 4, r16 = lane & 15;           \
  const int l8 = lane & 7, lr = lane >> 3;

#define GEMM_KLOOP(APTR, BPTR, KBYTES, NT)                                              \
  const f32x4 vzero = {0.f, 0.f, 0.f, 0.f};                                             \
  f32x4 acc[4][4];                                                                      \
  _Pragma("unroll") for (int i = 0; i < 4; ++i)                                         \
    _Pragma("unroll") for (int j = 0; j < 4; ++j) acc[i][j] = vzero;                    \
  auto stage = [&](int buf, int k0) {                                                   \
    _Pragma("unroll") for (int i = 0; i < 4; ++i) {                                     \
      const int c = w * 4 + i;                                                          \
      const int row = c * 8 + lr;                                                       \
      const int u = l8 ^ (row & 7);                                                     \
      gload16((const char*)(APTR) + (size_t)(bm * 128 + row) * (KBYTES) + k0 * 2 + u * 16, \
              AsB + buf * 16384 + c * 1024);                                            \
      gload16((const char*)(BPTR) + (size_t)(bn * 128 + row) * (KBYTES) + k0 * 2 + u * 16, \
              BsB + buf * 16384 + c * 1024);                                            \
    }                                                                                   \
  };                                                                                    \
  stage(0, 0);                                                                          \
  __syncthreads();                                                                      \
  for (int t = 0; t < (NT); ++t) {                                                      \
    const int cur = t & 1;                                                              \
    if (t + 1 < (NT)) stage(cur ^ 1, (t + 1) * 64);                                     \
    const char* Ac = AsB + cur * 16384;                                                 \
    const char* Bc = BsB + cur * 16384;                                                 \
    _Pragma("unroll") for (int kc = 0; kc < 2; ++kc) {                                  \
      short8 af[4], bf[4];                                                              \
      _Pragma("unroll") for (int mi = 0; mi < 4; ++mi) {                                \
        const int row = wm * 64 + mi * 16 + r16;                                        \
        af[mi] = *(const short8*)(Ac + row * 128 + ((((kc << 2) | g) ^ (r16 & 7)) << 4)); \
      }                                                                                 \
      _Pragma("unroll") for (int ni = 0; ni < 4; ++ni) {                                \
        const int row = wn * 64 + ni * 16 + r16;                                        \
        bf[ni] = *(const short8*)(Bc + row * 128 + ((((kc << 2) | g) ^ (r16 & 7)) << 4)); \
      }                                                                                 \
      _Pragma("unroll") for (int mi = 0; mi < 4; ++mi)                                  \
        _Pragma("unroll") for (int ni = 0; ni < 4; ++ni)                                \
          acc[mi][ni] = __builtin_amdgcn_mfma_f32_16x16x32_bf16(af[mi], bf[ni], acc[mi][ni], 0, 0, 0); \
    }                                                                                   \
    __syncthreads();                                                                    \
  }

// QKV GEMM: M=8192, N=1536, K=1024.  Writes Qb [8192][1024],
// Kb [b*4+g][2048][64], Vt [b*4+g][64][2048] (all bf16).
__global__ __launch_bounds__(256, 2) void gemm_qkv_kernel(
    const ushort_t* __restrict__ A, const ushort_t* __restrict__ Bt,
    const float* __restrict__ bias,
    ushort_t* __restrict__ Qb, ushort_t* __restrict__ Kb, ushort_t* __restrict__ Vt)
{
  __shared__ __align__(16) char AsB[32768];
  __shared__ __align__(16) char BsB[32768];
  // XCD swizzle: 768 blocks; XCD x gets bm-range [x*8, x*8+8) x all 12 bn.
  const int xcd = blockIdx.x & 7, ii = blockIdx.x >> 3;
  const int bm = xcd * 8 + (ii & 7), bn = ii >> 3;
  GEMM_IDS
  GEMM_KLOOP(A, Bt, 2048, 16)

  float bcol[4];
#pragma unroll
  for (int ni = 0; ni < 4; ++ni) bcol[ni] = bias[bn * 128 + wn * 64 + ni * 16 + r16];
  const int bb = bm >> 4;                    // batch
  if (bn < 8) {                              // ---- Q ----
#pragma unroll
    for (int mi = 0; mi < 4; ++mi)
#pragma unroll
      for (int ni = 0; ni < 4; ++ni) {
        const int col = bn * 128 + wn * 64 + ni * 16 + r16;
#pragma unroll
        for (int rr = 0; rr < 4; ++rr) {
          const int row = bm * 128 + wm * 64 + mi * 16 + g * 4 + rr;
          Qb[(size_t)row * 1024 + col] = f2bf(acc[mi][ni][rr] + bcol[ni]);
        }
      }
  } else if (bn < 10) {                      // ---- K ----
#pragma unroll
    for (int mi = 0; mi < 4; ++mi)
#pragma unroll
      for (int ni = 0; ni < 4; ++ni) {
        const int c = bn * 128 + wn * 64 + ni * 16 + r16 - 1024;
        const int gi = c >> 6, dd = c & 63;
#pragma unroll
        for (int rr = 0; rr < 4; ++rr) {
          const int row = bm * 128 + wm * 64 + mi * 16 + g * 4 + rr;
          const int s = row & 2047;
          Kb[((size_t)(bb * 4 + gi) * 2048 + s) * 64 + dd] = f2bf(acc[mi][ni][rr] + bcol[ni]);
        }
      }
  } else {                                   // ---- V -> transposed ----
#pragma unroll
    for (int mi = 0; mi < 4; ++mi) {
      const int s0 = (bm * 128 + wm * 64 + mi * 16 + g * 4) & 2047;
#pragma unroll
      for (int ni = 0; ni < 4; ++ni) {
        const int c = bn * 128 + wn * 64 + ni * 16 + r16 - 1280;
        const int gi = c >> 6, dd = c & 63;
        ushort4v pk;
#pragma unroll
        for (int rr = 0; rr < 4; ++rr) pk[rr] = f2bf(acc[mi][ni][rr] + bcol[ni]);
        *reinterpret_cast<ushort4v*>(Vt + ((size_t)(bb * 4 + gi) * 64 + dd) * 2048 + s0) = pk;
      }
    }
  }
}

// Output GEMM: M=8192, N=1024, K=1024, fp32 out + bias.
__global__ __launch_bounds__(256, 2) void gemm_out_kernel(
    const ushort_t* __restrict__ A, const ushort_t* __restrict__ Bt,
    const float* __restrict__ bias, float* __restrict__ Cout)
{
  __shared__ __align__(16) char AsB[32768];
  __shared__ __align__(16) char BsB[32768];
  // XCD swizzle: 512 blocks; XCD x gets bm-range [x*8, x*8+8) x all 8 bn.
  const int xcd = blockIdx.x & 7, ii = blockIdx.x >> 3;
  const int bm = xcd * 8 + (ii & 7), bn = ii >> 3;
  GEMM_IDS
  GEMM_KLOOP(A, Bt, 2048, 16)

  float bcol[4];
#pragma unroll
  for (int ni = 0; ni < 4; ++ni) bcol[ni] = bias[bn * 128 + wn * 64 + ni * 16 + r16];
#pragma unroll
  for (int mi = 0; mi < 4; ++mi)
#pragma unroll
    for (int ni = 0; ni < 4; ++ni) {
      const int col = bn * 128 + wn * 64 + ni * 16 + r16;
#pragma unroll
      for (int rr = 0; rr < 4; ++rr) {
        const int row = bm * 128 + wm * 64 + mi * 16 + g * 4 + rr;
        Cout[(size_t)row * 1024 + col] = acc[mi][ni][rr] + bcol[ni];
      }
    }
}

// ---------- attention (unchanged from round 2) ----------
__global__ __launch_bounds__(512, 4) void attn_kernel(
    const ushort_t* __restrict__ Qb, const ushort_t* __restrict__ Kb,
    const ushort_t* __restrict__ Vt, ushort_t* __restrict__ attout)
{
  __shared__ __align__(16) char KsB[8192];   // 2 x [32 keys][128B], XOR-swz (key&7)
  __shared__ __align__(16) char VsB[8192];   // 2 x [64 d][64B],     XOR-swz (d&3)
  const int fid = blockIdx.x + 32 * (blockIdx.y + 4 * blockIdx.z);
  const int j = fid >> 3;
  const int qt = (fid & 7) * 4 + (j >> 4);
  const int gg = j & 3, b = (j >> 2) & 3;

  const int tid = threadIdx.x;
  const int w = tid >> 6, lane = tid & 63;
  const int hw = w & 3, qh = w >> 2;
  const int h = gg * 4 + hw;
  const int g = lane >> 4, r16 = lane & 15;
  const int u0 = g >> 1;
  const int lowb = (g & 1) << 3;
  const int q0w = qt * 64 + qh * 32;

  Frag8 qf[2][2];
#pragma unroll
  for (int qs = 0; qs < 2; ++qs) {
    const char* qptr = (const char*)Qb + ((size_t)(b * 2048 + q0w + qs * 16 + r16) * 1024 + h * 64) * 2;
#pragma unroll
    for (int dc = 0; dc < 2; ++dc)
#pragma unroll
      for (int hh = 0; hh < 2; ++hh)
        qf[qs][dc].h[hh] = *(const short4v*)(qptr + dc * 64 + hh * 32 + g * 8);
  }

  const f32x4 vzero = {0.f, 0.f, 0.f, 0.f};
  f32x4 accO[2][4];
#pragma unroll
  for (int qs = 0; qs < 2; ++qs)
#pragma unroll
    for (int nt = 0; nt < 4; ++nt) accO[qs][nt] = vzero;
  float mrun[2] = {-1e30f, -1e30f};
  float lsum[2] = {0.f, 0.f};

  const char* KbB = (const char*)Kb + (size_t)(b * 4 + gg) * 2048 * 128;
  const char* VtB = (const char*)Vt + (size_t)(b * 4 + gg) * 2048 * 128;

  const int kb0 = (qt >= 8) ? (qt * 64 - 512) : 0;
  const int kend = qt * 64 + 64;

  auto stage = [&](int buf, int kb) {
    if (tid < 256) {
      const int rr = tid >> 3, pk = tid & 7;
      gload16(KbB + (size_t)(kb + rr) * 128 + ((pk ^ (rr & 7)) << 4),
              KsB + buf * 4096 + w * 1024);
    } else {
      const int u = tid - 256;
      const int d = u >> 2, pv = u & 3;
      gload16(VtB + (size_t)d * 4096 + kb * 2 + ((pv ^ (d & 3)) << 4),
              VsB + buf * 4096 + (w - 4) * 1024);
    }
  };

  stage(0, kb0);
  __syncthreads();
  int cur = 0;
  for (int kb = kb0; kb < kend; kb += 32) {
    if (kb + 32 < kend) stage(cur ^ 1, kb + 32);
    const bool active = (kb >= q0w - 512) && (kb <= q0w);
    if (active) {
      const char* Ks = KsB + cur * 4096;
      const char* Vs = VsB + cur * 4096;
      const bool full = (kb >= q0w - 480) && (kb <= q0w - 32);

      f32x4 st[2][2];
#pragma unroll
      for (int ki = 0; ki < 2; ++ki) {
        const int key = ki * 16 + r16;
        const int swz = key & 7;
        Frag8 kf0, kf1;
        kf0.h[0] = *(const short4v*)(Ks + key * 128 + (((0 + u0) ^ swz) << 4) + lowb);
        kf0.h[1] = *(const short4v*)(Ks + key * 128 + (((2 + u0) ^ swz) << 4) + lowb);
        kf1.h[0] = *(const short4v*)(Ks + key * 128 + (((4 + u0) ^ swz) << 4) + lowb);
        kf1.h[1] = *(const short4v*)(Ks + key * 128 + (((6 + u0) ^ swz) << 4) + lowb);
#pragma unroll
        for (int qs = 0; qs < 2; ++qs) {
          st[qs][ki] = __builtin_amdgcn_mfma_f32_16x16x32_bf16(kf0.v, qf[qs][0].v, vzero, 0, 0, 0);
          st[qs][ki] = __builtin_amdgcn_mfma_f32_16x16x32_bf16(kf1.v, qf[qs][1].v, st[qs][ki], 0, 0, 0);
        }
      }

      Frag8 pf[2];
#pragma unroll
      for (int qs = 0; qs < 2; ++qs) {
        float pr[8];
        float tm = -INFINITY;
#pragma unroll
        for (int ki = 0; ki < 2; ++ki)
#pragma unroll
          for (int r = 0; r < 4; ++r) {
            float s = st[qs][ki][r] * 0.180336881f;
            if (!full) {
              const int key = kb + ki * 16 + g * 4 + r;
              const int q = q0w + qs * 16 + r16;
              const bool valid = (key <= q) && (key + 512 > q);
              s = valid ? s : -INFINITY;
            }
            pr[ki * 4 + r] = s;
            tm = fmaxf(tm, s);
          }
        tm = fmaxf(tm, __shfl_xor(tm, 16));
        tm = fmaxf(tm, __shfl_xor(tm, 32));
        const float mnew = fmaxf(mrun[qs], tm);
        const float corr = exp2f(mrun[qs] - mnew);
        float tsum = 0.f;
#pragma unroll
        for (int i = 0; i < 8; ++i) {
          const float e = exp2f(pr[i] - mnew);
          pr[i] = e;
          tsum += e;
        }
        tsum += __shfl_xor(tsum, 16);
        tsum += __shfl_xor(tsum, 32);
        lsum[qs] = lsum[qs] * corr + tsum;
        mrun[qs] = mnew;
        float cq[4];
#pragma unroll
        for (int rr = 0; rr < 4; ++rr) cq[rr] = __shfl(corr, g * 4 + rr);
#pragma unroll
        for (int nt = 0; nt < 4; ++nt)
#pragma unroll
          for (int rr = 0; rr < 4; ++rr) accO[qs][nt][rr] *= cq[rr];
#pragma unroll
        for (int jj = 0; jj < 4; ++jj) {
          pf[qs].v[jj]     = (short)f2bf(pr[jj]);
          pf[qs].v[4 + jj] = (short)f2bf(pr[4 + jj]);
        }
      }

#pragma unroll
      for (int nt = 0; nt < 4; ++nt) {
        const int d = nt * 16 + r16;
        Frag8 vf;
        vf.h[0] = *(const short4v*)(Vs + d * 64 + (((0 + u0) ^ (d & 3)) << 4) + lowb);
        vf.h[1] = *(const short4v*)(Vs + d * 64 + (((2 + u0) ^ (d & 3)) << 4) + lowb);
#pragma unroll
        for (int qs = 0; qs < 2; ++qs)
          accO[qs][nt] = __builtin_amdgcn_mfma_f32_16x16x32_bf16(pf[qs].v, vf.v, accO[qs][nt], 0, 0, 0);
      }
    }
    __syncthreads();
    cur ^= 1;
  }

#pragma unroll
  for (int qs = 0; qs < 2; ++qs) {
    const float linv = 1.f / lsum[qs];
    float lq[4];
#pragma unroll
    for (int rr = 0; rr < 4; ++rr) lq[rr] = __shfl(linv, g * 4 + rr);
#pragma unroll
    for (int nt = 0; nt < 4; ++nt) {
      const int ocol = h * 64 + nt * 16 + r16;
#pragma unroll
      for (int rr = 0; rr < 4; ++rr) {
        const int orow = b * 2048 + q0w + qs * 16 + g * 4 + rr;
        attout[(size_t)orow * 1024 + ocol] = f2bf(accO[qs][nt][rr] * lq[rr]);
      }
    }
  }
}

// ---------- launch ----------
extern "C" void kernel_launch(void* const* d_in, const int* in_sizes, int n_in,
                              void* d_out, int out_size, void* d_ws, size_t ws_size,
                              hipStream_t stream) {
  (void)in_sizes; (void)n_in; (void)out_size; (void)ws_size;
  const float* x  = (const float*)d_in[0];
  const float* Wq = (const float*)d_in[1];
  const float* bq = (const float*)d_in[2];
  const float* Wk = (const float*)d_in[3];
  const float* bk = (const float*)d_in[4];
  const float* Wv = (const float*)d_in[5];
  const float* bv = (const float*)d_in[6];
  const float* Wo = (const float*)d_in[7];
  const float* bo = (const float*)d_in[8];

  char* ws = (char*)d_ws;
  ushort_t* Qb   = (ushort_t*)(ws + 0);          // 8192x1024 bf16 = 16 MiB
  ushort_t* Kb   = (ushort_t*)(ws + 16777216);   // 16x2048x64 bf16 = 4 MiB
  ushort_t* Vt   = (ushort_t*)(ws + 20971520);   // 16x64x2048 bf16 = 4 MiB
  ushort_t* wt   = (ushort_t*)(ws + 25165824);   // 2560x1024 bf16 = 5 MiB
  float*    bqkv = (float*)   (ws + 30408704);   // 1536 fp32
  ushort_t* xb   = (ushort_t*)(ws + 30416896);   // 8192x1024 bf16 = 16 MiB
  ushort_t* att  = (ushort_t*)(ws + 47194112);   // 8192x1024 bf16 = 16 MiB

  cast_x_kernel<<<8192, 256, 0, stream>>>(x, xb);
  transpose_w_kernel<<<dim3(80, 32), 256, 0, stream>>>(Wq, Wk, Wv, Wo, wt);
  prep_bias_kernel<<<6, 256, 0, stream>>>(bq, bk, bv, bqkv);
  gemm_qkv_kernel<<<768, 256, 0, stream>>>(xb, wt, bqkv, Qb, Kb, Vt);
  attn_kernel<<<dim3(32, 4, 4), 512, 0, stream>>>(Qb, Kb, Vt, att);
  gemm_out_kernel<<<512, 256, 0, stream>>>(att, wt + (size_t)1536 * 1024, bo, (float*)d_out);
}

// Round 4
// 120.802 us; speedup vs baseline: 1.9407x; 1.1309x over previous
//
#include <hip/hip_runtime.h>
#include <cstdint>
#include <cstddef>

// ---------- types ----------
typedef __attribute__((ext_vector_type(8))) short short8;
typedef __attribute__((ext_vector_type(4))) short short4v;
typedef __attribute__((ext_vector_type(4))) float f32x4;
typedef __attribute__((ext_vector_type(4))) unsigned short ushort4v;
typedef unsigned short ushort_t;

union Frag8 { short4v h[2]; short8 v; };
union PFrag { unsigned int w[4]; short8 v; };

__device__ __forceinline__ ushort_t f2bf(float f) {
  unsigned int u = __builtin_bit_cast(unsigned int, f);
  u += 0x7FFFu + ((u >> 16) & 1u);   // RNE; inputs finite
  return (ushort_t)(u >> 16);
}

__device__ __forceinline__ void gload16(const void* g, void* l) {
  __builtin_amdgcn_global_load_lds(
      (const __attribute__((address_space(1))) unsigned int*)g,
      (__attribute__((address_space(3))) unsigned int*)l, 16, 0, 0);
}

// ---------- prep kernels ----------
__global__ void cast_x_kernel(const float* __restrict__ x, ushort_t* __restrict__ o) {
  int i = (blockIdx.x * 256 + threadIdx.x) * 4;
  const float4 v = *reinterpret_cast<const float4*>(x + i);
  ushort4v r = { f2bf(v.x), f2bf(v.y), f2bf(v.z), f2bf(v.w) };
  *reinterpret_cast<ushort4v*>(o + i) = r;
}

// Tiled transpose: W[k][n] fp32 -> Wt[n][k] bf16.  Wt rows: 0..1023 Wq^T,
// 1024..1279 Wk^T, 1280..1535 Wv^T, 1536..2559 Wo^T.
__global__ __launch_bounds__(256) void transpose_w_kernel(
    const float* __restrict__ Wq, const float* __restrict__ Wk,
    const float* __restrict__ Wv, const float* __restrict__ Wo,
    ushort_t* __restrict__ Wt) {
  __shared__ float tile[32][33];
  const int tn = blockIdx.x, tk = blockIdx.y;
  const int n0 = tn * 32;
  const float* W; int ldn, nloc;
  if      (n0 < 1024) { W = Wq; ldn = 1024; nloc = n0; }
  else if (n0 < 1280) { W = Wk; ldn = 256;  nloc = n0 - 1024; }
  else if (n0 < 1536) { W = Wv; ldn = 256;  nloc = n0 - 1280; }
  else                { W = Wo; ldn = 1024; nloc = n0 - 1536; }
  const int t = threadIdx.x;
  const int sr = t >> 3, sc = (t & 7) * 4;
  const float4 v = *reinterpret_cast<const float4*>(W + (size_t)(tk * 32 + sr) * ldn + nloc + sc);
  tile[sr][sc] = v.x; tile[sr][sc + 1] = v.y; tile[sr][sc + 2] = v.z; tile[sr][sc + 3] = v.w;
  __syncthreads();
  const int wr = t >> 3, wc = (t & 7) * 4;
  ushort4v o = { f2bf(tile[wc][wr]), f2bf(tile[wc + 1][wr]),
                 f2bf(tile[wc + 2][wr]), f2bf(tile[wc + 3][wr]) };
  *reinterpret_cast<ushort4v*>(Wt + (size_t)(n0 + wr) * 1024 + tk * 32 + wc) = o;
}

__global__ void prep_bias_kernel(const float* __restrict__ bq, const float* __restrict__ bk,
                                 const float* __restrict__ bv, float* __restrict__ bqkv) {
  int t = blockIdx.x * 256 + threadIdx.x;
  if (t < 1536) bqkv[t] = (t < 1024) ? bq[t] : (t < 1280) ? bk[t - 1024] : bv[t - 1280];
}

// ---------- GEMM core ----------
// 128x128 tile, BK=64 (128B LDS rows), 4 waves (2x2 of 64x64), 16x16x32 bf16 MFMA.
// Fragments: consistent-kappa contiguous 16B per lane -> single ds_read_b128.
// LDS 16B-unit swizzle U' = U ^ (row&7): conflict-free.  Staging: linear LDS
// dest, pre-swizzled global source (rule 21).  Double-buffered, 1 barrier/iter.
#define GEMM_IDS \
  const int tid = threadIdx.x;                        \
  const int w = tid >> 6, lane = tid & 63;            \
  const int wm = w >> 1, wn = w & 1;                  \
  const int g = lane >> 4, r16 = lane & 15;           \
  const int l8 = lane & 7, lr = lane >> 3;

#define GEMM_KLOOP(APTR, BPTR, KBYTES, NT)                                              \
  const f32x4 vzero = {0.f, 0.f, 0.f, 0.f};                                             \
  f32x4 acc[4][4];                                                                      \
  _Pragma("unroll") for (int i = 0; i < 4; ++i)                                         \
    _Pragma("unroll") for (int j = 0; j < 4; ++j) acc[i][j] = vzero;                    \
  auto stage = [&](int buf, int k0) {                                                   \
    _Pragma("unroll") for (int i = 0; i < 4; ++i) {                                     \
      const int c = w * 4 + i;                                                          \
      const int row = c * 8 + lr;                                                       \
      const int u = l8 ^ (row & 7);                                                     \
      gload16((const char*)(APTR) + (size_t)(bm * 128 + row) * (KBYTES) + k0 * 2 + u * 16, \
              AsB + buf * 16384 + c * 1024);                                            \
      gload16((const char*)(BPTR) + (size_t)(bn * 128 + row) * (KBYTES) + k0 * 2 + u * 16, \
              BsB + buf * 16384 + c * 1024);                                            \
    }                                                                                   \
  };                                                                                    \
  stage(0, 0);                                                                          \
  __syncthreads();                                                                      \
  for (int t = 0; t < (NT); ++t) {                                                      \
    const int cur = t & 1;                                                              \
    if (t + 1 < (NT)) stage(cur ^ 1, (t + 1) * 64);                                     \
    const char* Ac = AsB + cur * 16384;                                                 \
    const char* Bc = BsB + cur * 16384;                                                 \
    _Pragma("unroll") for (int kc = 0; kc < 2; ++kc) {                                  \
      short8 af[4], bf[4];                                                              \
      _Pragma("unroll") for (int mi = 0; mi < 4; ++mi) {                                \
        const int row = wm * 64 + mi * 16 + r16;                                        \
        af[mi] = *(const short8*)(Ac + row * 128 + ((((kc << 2) | g) ^ (r16 & 7)) << 4)); \
      }                                                                                 \
      _Pragma("unroll") for (int ni = 0; ni < 4; ++ni) {                                \
        const int row = wn * 64 + ni * 16 + r16;                                        \
        bf[ni] = *(const short8*)(Bc + row * 128 + ((((kc << 2) | g) ^ (r16 & 7)) << 4)); \
      }                                                                                 \
      _Pragma("unroll") for (int mi = 0; mi < 4; ++mi)                                  \
        _Pragma("unroll") for (int ni = 0; ni < 4; ++ni)                                \
          acc[mi][ni] = __builtin_amdgcn_mfma_f32_16x16x32_bf16(af[mi], bf[ni], acc[mi][ni], 0, 0, 0); \
    }                                                                                   \
    __syncthreads();                                                                    \
  }

// QKV GEMM: M=8192, N=1536, K=1024.  Writes Qb [8192][1024],
// Kb [b*4+g][2048][64], Vt [b*4+g][64][2048] (all bf16).
__global__ __launch_bounds__(256, 2) void gemm_qkv_kernel(
    const ushort_t* __restrict__ A, const ushort_t* __restrict__ Bt,
    const float* __restrict__ bias,
    ushort_t* __restrict__ Qb, ushort_t* __restrict__ Kb, ushort_t* __restrict__ Vt)
{
  __shared__ __align__(16) char AsB[32768];
  __shared__ __align__(16) char BsB[32768];
  const int xcd = blockIdx.x & 7, ii = blockIdx.x >> 3;
  const int bm = xcd * 8 + (ii & 7), bn = ii >> 3;
  GEMM_IDS
  GEMM_KLOOP(A, Bt, 2048, 16)

  float bcol[4];
#pragma unroll
  for (int ni = 0; ni < 4; ++ni) bcol[ni] = bias[bn * 128 + wn * 64 + ni * 16 + r16];
  const int bb = bm >> 4;                    // batch
  if (bn < 8) {                              // ---- Q ----
#pragma unroll
    for (int mi = 0; mi < 4; ++mi)
#pragma unroll
      for (int ni = 0; ni < 4; ++ni) {
        const int col = bn * 128 + wn * 64 + ni * 16 + r16;
#pragma unroll
        for (int rr = 0; rr < 4; ++rr) {
          const int row = bm * 128 + wm * 64 + mi * 16 + g * 4 + rr;
          Qb[(size_t)row * 1024 + col] = f2bf(acc[mi][ni][rr] + bcol[ni]);
        }
      }
  } else if (bn < 10) {                      // ---- K ----
#pragma unroll
    for (int mi = 0; mi < 4; ++mi)
#pragma unroll
      for (int ni = 0; ni < 4; ++ni) {
        const int c = bn * 128 + wn * 64 + ni * 16 + r16 - 1024;
        const int gi = c >> 6, dd = c & 63;
#pragma unroll
        for (int rr = 0; rr < 4; ++rr) {
          const int row = bm * 128 + wm * 64 + mi * 16 + g * 4 + rr;
          const int s = row & 2047;
          Kb[((size_t)(bb * 4 + gi) * 2048 + s) * 64 + dd] = f2bf(acc[mi][ni][rr] + bcol[ni]);
        }
      }
  } else {                                   // ---- V -> transposed ----
#pragma unroll
    for (int mi = 0; mi < 4; ++mi) {
      const int s0 = (bm * 128 + wm * 64 + mi * 16 + g * 4) & 2047;
#pragma unroll
      for (int ni = 0; ni < 4; ++ni) {
        const int c = bn * 128 + wn * 64 + ni * 16 + r16 - 1280;
        const int gi = c >> 6, dd = c & 63;
        ushort4v pk;
#pragma unroll
        for (int rr = 0; rr < 4; ++rr) pk[rr] = f2bf(acc[mi][ni][rr] + bcol[ni]);
        *reinterpret_cast<ushort4v*>(Vt + ((size_t)(bb * 4 + gi) * 64 + dd) * 2048 + s0) = pk;
      }
    }
  }
}

// Output GEMM: M=8192, N=1024, K=1024, fp32 out + bias.
__global__ __launch_bounds__(256, 2) void gemm_out_kernel(
    const ushort_t* __restrict__ A, const ushort_t* __restrict__ Bt,
    const float* __restrict__ bias, float* __restrict__ Cout)
{
  __shared__ __align__(16) char AsB[32768];
  __shared__ __align__(16) char BsB[32768];
  const int xcd = blockIdx.x & 7, ii = blockIdx.x >> 3;
  const int bm = xcd * 8 + (ii & 7), bn = ii >> 3;
  GEMM_IDS
  GEMM_KLOOP(A, Bt, 2048, 16)

  float bcol[4];
#pragma unroll
  for (int ni = 0; ni < 4; ++ni) bcol[ni] = bias[bn * 128 + wn * 64 + ni * 16 + r16];
#pragma unroll
  for (int mi = 0; mi < 4; ++mi)
#pragma unroll
    for (int ni = 0; ni < 4; ++ni) {
      const int col = bn * 128 + wn * 64 + ni * 16 + r16;
#pragma unroll
      for (int rr = 0; rr < 4; ++rr) {
        const int row = bm * 128 + wm * 64 + mi * 16 + g * 4 + rr;
        Cout[(size_t)row * 1024 + col] = acc[mi][ni][rr] + bcol[ni];
      }
    }
}

// ---------- attention ----------
// Block = (qtile 64, group, batch); 8 waves = 4 heads x 2 query-halves.
// KVBLK=64, double-buffered; static-max softmax (scores bounded ~|3|, no
// overflow risk); masked scores -> -inf -> exp2=0.  Swapped QK^T.
__global__ __launch_bounds__(512, 2) void attn_kernel(
    const ushort_t* __restrict__ Qb, const ushort_t* __restrict__ Kb,
    const ushort_t* __restrict__ Vt, ushort_t* __restrict__ attout)
{
  __shared__ __align__(16) char KsB[16384];  // 2 x [64 keys][128B], swz (key&7)
  __shared__ __align__(16) char VsB[16384];  // 2 x [64 d][64 keys*2B], swz (d&7)
  const int fid = blockIdx.x + 32 * (blockIdx.y + 4 * blockIdx.z);
  const int j = fid >> 3;
  const int qt = (fid & 7) * 4 + (j >> 4);
  const int gg = j & 3, b = (j >> 2) & 3;

  const int tid = threadIdx.x;
  const int w = tid >> 6, lane = tid & 63;
  const int hw = w & 3, qh = w >> 2;
  const int h = gg * 4 + hw;
  const int g = lane >> 4, r16 = lane & 15;
  const int u0 = g >> 1;
  const int lowb = (g & 1) << 3;
  const int q0w = qt * 64 + qh * 32;

  // Q fragments, contiguous kappa: chunk dc element j -> d = dc*32 + g*8 + j
  short8 qf[2][2];
#pragma unroll
  for (int qs = 0; qs < 2; ++qs) {
    const char* qptr = (const char*)Qb + ((size_t)(b * 2048 + q0w + qs * 16 + r16) * 1024 + h * 64) * 2;
#pragma unroll
    for (int dc = 0; dc < 2; ++dc)
      qf[qs][dc] = *(const short8*)(qptr + dc * 64 + g * 16);
  }

  const f32x4 vzero = {0.f, 0.f, 0.f, 0.f};
  f32x4 accO[2][4];
#pragma unroll
  for (int qs = 0; qs < 2; ++qs)
#pragma unroll
    for (int nt = 0; nt < 4; ++nt) accO[qs][nt] = vzero;
  float lsum[2] = {0.f, 0.f};

  const char* KbB = (const char*)Kb + (size_t)(b * 4 + gg) * 2048 * 128;  // key rows 128B
  const char* VtB = (const char*)Vt + (size_t)(b * 4 + gg) * 64 * 4096;   // d rows 4096B

  const int kb0 = (qt >= 8) ? (qt * 64 - 512) : 0;
  const int NT = (qt * 64 + 64 - kb0) >> 6;

  const int srr = tid >> 3, spk = tid & 7;
  auto stage = [&](int buf, int kb) {
    gload16(KbB + (size_t)(kb + srr) * 128 + ((spk ^ (srr & 7)) << 4),
            KsB + buf * 8192 + tid * 16);
    gload16(VtB + (size_t)srr * 4096 + (size_t)kb * 2 + ((spk ^ (srr & 7)) << 4),
            VsB + buf * 8192 + tid * 16);
  };

  stage(0, kb0);
  __syncthreads();
  for (int t = 0; t < NT; ++t) {
    const int kb = kb0 + t * 64;
    const int cur = t & 1;
    if (t + 1 < NT) stage(cur ^ 1, kb + 64);
    const char* Ks = KsB + cur * 8192;
    const char* Vs = VsB + cur * 8192;
    const bool full = (kb >= q0w - 480) && (kb <= q0w - 63);

    // QK^T: S^T tile [64 keys][32 q] per wave
    f32x4 st[2][4];
#pragma unroll
    for (int ki = 0; ki < 4; ++ki) {
      const int key = ki * 16 + r16;
      const int swz = key & 7;
      const short8 kf0 = *(const short8*)(Ks + key * 128 + ((g ^ swz) << 4));
      const short8 kf1 = *(const short8*)(Ks + key * 128 + (((4 + g) ^ swz) << 4));
#pragma unroll
      for (int qs = 0; qs < 2; ++qs) {
        st[qs][ki] = __builtin_amdgcn_mfma_f32_16x16x32_bf16(kf0, qf[qs][0], vzero, 0, 0, 0);
        st[qs][ki] = __builtin_amdgcn_mfma_f32_16x16x32_bf16(kf1, qf[qs][1], st[qs][ki], 0, 0, 0);
      }
    }

    // static-max softmax: p = exp2(s*log2e/8); masked -> 0
    PFrag pf[2][2];
#pragma unroll
    for (int qs = 0; qs < 2; ++qs) {
      const int q = q0w + qs * 16 + r16;
#pragma unroll
      for (int ki = 0; ki < 4; ++ki)
#pragma unroll
        for (int r = 0; r < 4; ++r) {
          float s = st[qs][ki][r] * 0.180336881f;
          if (!full) {
            const int key = kb + ki * 16 + g * 4 + r;
            const bool valid = (key <= q) && (key + 512 > q);
            s = valid ? s : -INFINITY;
          }
          st[qs][ki][r] = __builtin_amdgcn_exp2f(s);
        }
      float tk[4];
#pragma unroll
      for (int ki = 0; ki < 4; ++ki)
        tk[ki] = (st[qs][ki][0] + st[qs][ki][1]) + (st[qs][ki][2] + st[qs][ki][3]);
      lsum[qs] += (tk[0] + tk[1]) + (tk[2] + tk[3]);
#pragma unroll
      for (int c = 0; c < 2; ++c)
#pragma unroll
        for (int pr = 0; pr < 2; ++pr) {
          asm("v_cvt_pk_bf16_f32 %0, %1, %2"
              : "=v"(pf[qs][c].w[pr * 2])
              : "v"(st[qs][2 * c + pr][0]), "v"(st[qs][2 * c + pr][1]));
          asm("v_cvt_pk_bf16_f32 %0, %1, %2"
              : "=v"(pf[qs][c].w[pr * 2 + 1])
              : "v"(st[qs][2 * c + pr][2]), "v"(st[qs][2 * c + pr][3]));
        }
    }

    // PV: kappa_P = kappa_V = 16*(j>>2) + 4g + (j&3) within each 32-key chunk
#pragma unroll
    for (int c = 0; c < 2; ++c)
#pragma unroll
      for (int nt = 0; nt < 4; ++nt) {
        const int d = nt * 16 + r16;
        const int swz = d & 7;
        Frag8 vf;
        vf.h[0] = *(const short4v*)(Vs + d * 128 + (((c * 4 + u0) ^ swz) << 4) + lowb);
        vf.h[1] = *(const short4v*)(Vs + d * 128 + (((c * 4 + 2 + u0) ^ swz) << 4) + lowb);
#pragma unroll
        for (int qs = 0; qs < 2; ++qs)
          accO[qs][nt] = __builtin_amdgcn_mfma_f32_16x16x32_bf16(pf[qs][c].v, vf.v, accO[qs][nt], 0, 0, 0);
      }
    __syncthreads();
  }

#pragma unroll
  for (int qs = 0; qs < 2; ++qs) {
    float ts = lsum[qs];
    ts += __shfl_xor(ts, 16);
    ts += __shfl_xor(ts, 32);
    const float linv = 1.f / ts;
    float lq[4];
#pragma unroll
    for (int rr = 0; rr < 4; ++rr) lq[rr] = __shfl(linv, g * 4 + rr);
#pragma unroll
    for (int nt = 0; nt < 4; ++nt) {
      const int ocol = h * 64 + nt * 16 + r16;
#pragma unroll
      for (int rr = 0; rr < 4; ++rr) {
        const int orow = b * 2048 + q0w + qs * 16 + g * 4 + rr;
        attout[(size_t)orow * 1024 + ocol] = f2bf(accO[qs][nt][rr] * lq[rr]);
      }
    }
  }
}

// ---------- launch ----------
extern "C" void kernel_launch(void* const* d_in, const int* in_sizes, int n_in,
                              void* d_out, int out_size, void* d_ws, size_t ws_size,
                              hipStream_t stream) {
  (void)in_sizes; (void)n_in; (void)out_size; (void)ws_size;
  const float* x  = (const float*)d_in[0];
  const float* Wq = (const float*)d_in[1];
  const float* bq = (const float*)d_in[2];
  const float* Wk = (const float*)d_in[3];
  const float* bk = (const float*)d_in[4];
  const float* Wv = (const float*)d_in[5];
  const float* bv = (const float*)d_in[6];
  const float* Wo = (const float*)d_in[7];
  const float* bo = (const float*)d_in[8];

  char* ws = (char*)d_ws;
  ushort_t* Qb   = (ushort_t*)(ws + 0);          // 8192x1024 bf16 = 16 MiB
  ushort_t* Kb   = (ushort_t*)(ws + 16777216);   // 16x2048x64 bf16 = 4 MiB
  ushort_t* Vt   = (ushort_t*)(ws + 20971520);   // 16x64x2048 bf16 = 4 MiB
  ushort_t* wt   = (ushort_t*)(ws + 25165824);   // 2560x1024 bf16 = 5 MiB
  float*    bqkv = (float*)   (ws + 30408704);   // 1536 fp32
  ushort_t* xb   = (ushort_t*)(ws + 30416896);   // 8192x1024 bf16 = 16 MiB
  ushort_t* att  = (ushort_t*)(ws + 47194112);   // 8192x1024 bf16 = 16 MiB

  cast_x_kernel<<<8192, 256, 0, stream>>>(x, xb);
  transpose_w_kernel<<<dim3(80, 32), 256, 0, stream>>>(Wq, Wk, Wv, Wo, wt);
  prep_bias_kernel<<<6, 256, 0, stream>>>(bq, bk, bv, bqkv);
  gemm_qkv_kernel<<<768, 256, 0, stream>>>(xb, wt, bqkv, Qb, Kb, Vt);
  attn_kernel<<<dim3(32, 4, 4), 512, 0, stream>>>(Qb, Kb, Vt, att);
  gemm_out_kernel<<<512, 256, 0, stream>>>(att, wt + (size_t)1536 * 1024, bo, (float*)d_out);
}

// Round 5
// 118.739 us; speedup vs baseline: 1.9744x; 1.0174x over previous
//
#include <hip/hip_runtime.h>
#include <cstdint>
#include <cstddef>

// ---------- types ----------
typedef __attribute__((ext_vector_type(8))) short short8;
typedef __attribute__((ext_vector_type(4))) short short4v;
typedef __attribute__((ext_vector_type(4))) float f32x4;
typedef __attribute__((ext_vector_type(4))) unsigned short ushort4v;
typedef unsigned short ushort_t;

union Frag8 { short4v h[2]; short8 v; };
union PFrag { unsigned int w[4]; short8 v; };

__device__ __forceinline__ ushort_t f2bf(float f) {
  unsigned int u = __builtin_bit_cast(unsigned int, f);
  u += 0x7FFFu + ((u >> 16) & 1u);   // RNE; inputs finite
  return (ushort_t)(u >> 16);
}

__device__ __forceinline__ void gload16(const void* g, void* l) {
  __builtin_amdgcn_global_load_lds(
      (const __attribute__((address_space(1))) unsigned int*)g,
      (__attribute__((address_space(3))) unsigned int*)l, 16, 0, 0);
}

// ---------- prep kernels ----------
__global__ void cast_x_kernel(const float* __restrict__ x, ushort_t* __restrict__ o) {
  int i = (blockIdx.x * 256 + threadIdx.x) * 4;
  const float4 v = *reinterpret_cast<const float4*>(x + i);
  ushort4v r = { f2bf(v.x), f2bf(v.y), f2bf(v.z), f2bf(v.w) };
  *reinterpret_cast<ushort4v*>(o + i) = r;
}

// Tiled transpose: W[k][n] fp32 -> Wt[n][k] bf16.  Wt rows: 0..1023 Wq^T,
// 1024..1279 Wk^T, 1280..1535 Wv^T, 1536..2559 Wo^T.
__global__ __launch_bounds__(256) void transpose_w_kernel(
    const float* __restrict__ Wq, const float* __restrict__ Wk,
    const float* __restrict__ Wv, const float* __restrict__ Wo,
    ushort_t* __restrict__ Wt) {
  __shared__ float tile[32][33];
  const int tn = blockIdx.x, tk = blockIdx.y;
  const int n0 = tn * 32;
  const float* W; int ldn, nloc;
  if      (n0 < 1024) { W = Wq; ldn = 1024; nloc = n0; }
  else if (n0 < 1280) { W = Wk; ldn = 256;  nloc = n0 - 1024; }
  else if (n0 < 1536) { W = Wv; ldn = 256;  nloc = n0 - 1280; }
  else                { W = Wo; ldn = 1024; nloc = n0 - 1536; }
  const int t = threadIdx.x;
  const int sr = t >> 3, sc = (t & 7) * 4;
  const float4 v = *reinterpret_cast<const float4*>(W + (size_t)(tk * 32 + sr) * ldn + nloc + sc);
  tile[sr][sc] = v.x; tile[sr][sc + 1] = v.y; tile[sr][sc + 2] = v.z; tile[sr][sc + 3] = v.w;
  __syncthreads();
  const int wr = t >> 3, wc = (t & 7) * 4;
  ushort4v o = { f2bf(tile[wc][wr]), f2bf(tile[wc + 1][wr]),
                 f2bf(tile[wc + 2][wr]), f2bf(tile[wc + 3][wr]) };
  *reinterpret_cast<ushort4v*>(Wt + (size_t)(n0 + wr) * 1024 + tk * 32 + wc) = o;
}

__global__ void prep_bias_kernel(const float* __restrict__ bq, const float* __restrict__ bk,
                                 const float* __restrict__ bv, float* __restrict__ bqkv) {
  int t = blockIdx.x * 256 + threadIdx.x;
  if (t < 1536) bqkv[t] = (t < 1024) ? bq[t] : (t < 1280) ? bk[t - 1024] : bv[t - 1280];
}

// ---------- GEMM core ----------
// Block tile 256x128, BK=32, 4 waves (2x2), per-wave 128x64 (acc[8][4]),
// 16x16x32 bf16 MFMA.  3-stage LDS pipeline (24 KB/stage, 72 KB total),
// counted s_waitcnt vmcnt(6) (2 stages always in flight), raw s_barrier,
// setprio around the 32-MFMA cluster.  LDS rows are 64 B (4x16B units);
// phys unit = logical ^ ((row>>1)&3) -> every bank gets exactly 8 words per
// wave b128 read (minimum, conflict-free).  Staging: linear LDS dest,
// pre-swizzled global source (both-sides rule).  K=1024 fixed (32 iters).
#define GEMM_IDS \
  const int tid = threadIdx.x;                        \
  const int w = tid >> 6, lane = tid & 63;            \
  const int wm = w >> 1, wn = w & 1;                  \
  const int g = lane >> 4, r16 = lane & 15;

#define GEMM_KLOOP(APTR, BPTR)                                                          \
  const f32x4 vzero = {0.f, 0.f, 0.f, 0.f};                                             \
  f32x4 acc[8][4];                                                                      \
  _Pragma("unroll") for (int i = 0; i < 8; ++i)                                         \
    _Pragma("unroll") for (int j = 0; j < 4; ++j) acc[i][j] = vzero;                    \
  const int su = (lane & 3) ^ ((lane >> 3) & 3);                                        \
  const int sr = lane >> 2;                                                             \
  auto stage = [&](int s, int k0) {                                                     \
    char* base = LdsB + s * 24576;                                                      \
    _Pragma("unroll") for (int i = 0; i < 4; ++i) {                                     \
      const int c = w * 4 + i;                                                          \
      gload16((const char*)(APTR) + (size_t)(bm * 256 + c * 16 + sr) * 2048 + k0 * 2 + su * 16, \
              base + c * 1024);                                                         \
    }                                                                                   \
    _Pragma("unroll") for (int i = 0; i < 2; ++i) {                                     \
      const int c = w * 2 + i;                                                          \
      gload16((const char*)(BPTR) + (size_t)(bn * 128 + c * 16 + sr) * 2048 + k0 * 2 + su * 16, \
              base + 16384 + c * 1024);                                                 \
    }                                                                                   \
  };                                                                                    \
  stage(0, 0);                                                                          \
  stage(1, 32);                                                                         \
  const int fsw = (g ^ ((r16 >> 1) & 3)) << 4;                                          \
  for (int t = 0; t < 32; ++t) {                                                        \
    if (t < 31) { asm volatile("s_waitcnt vmcnt(6) lgkmcnt(0)" ::: "memory"); }         \
    else        { asm volatile("s_waitcnt vmcnt(0) lgkmcnt(0)" ::: "memory"); }         \
    __builtin_amdgcn_s_barrier();                                                       \
    if (t + 2 < 32) stage((t + 2) % 3, (t + 2) * 32);                                   \
    const char* Ab = LdsB + (t % 3) * 24576;                                            \
    const char* Bb = Ab + 16384;                                                        \
    short8 af[8], bf[4];                                                                \
    _Pragma("unroll") for (int mi = 0; mi < 8; ++mi)                                    \
      af[mi] = *(const short8*)(Ab + (wm * 128 + mi * 16 + r16) * 64 + fsw);            \
    _Pragma("unroll") for (int ni = 0; ni < 4; ++ni)                                    \
      bf[ni] = *(const short8*)(Bb + (wn * 64 + ni * 16 + r16) * 64 + fsw);             \
    __builtin_amdgcn_s_setprio(1);                                                      \
    _Pragma("unroll") for (int mi = 0; mi < 8; ++mi)                                    \
      _Pragma("unroll") for (int ni = 0; ni < 4; ++ni)                                  \
        acc[mi][ni] = __builtin_amdgcn_mfma_f32_16x16x32_bf16(af[mi], bf[ni], acc[mi][ni], 0, 0, 0); \
    __builtin_amdgcn_s_setprio(0);                                                      \
  }

// QKV GEMM: M=8192, N=1536, K=1024.  Writes Qb [8192][1024],
// Kb [b*4+g][2048][64], Vt [b*4+g][64][2048] (all bf16).
__global__ __launch_bounds__(256, 2) void gemm_qkv_kernel(
    const ushort_t* __restrict__ A, const ushort_t* __restrict__ Bt,
    const float* __restrict__ bias,
    ushort_t* __restrict__ Qb, ushort_t* __restrict__ Kb, ushort_t* __restrict__ Vt)
{
  __shared__ __align__(16) char LdsB[73728];
  // 384 blocks; XCD x gets bm in [x*4, x*4+4) x all 12 bn (A-slab+B <= ~4MB L2).
  const int xcd = blockIdx.x & 7, ii = blockIdx.x >> 3;   // ii in [0,48)
  const int bm = xcd * 4 + ii / 12, bn = ii % 12;
  GEMM_IDS
  GEMM_KLOOP(A, Bt)

  float bcol[4];
#pragma unroll
  for (int ni = 0; ni < 4; ++ni) bcol[ni] = bias[bn * 128 + wn * 64 + ni * 16 + r16];
  if (bn < 8) {                              // ---- Q ----
#pragma unroll
    for (int mi = 0; mi < 8; ++mi)
#pragma unroll
      for (int ni = 0; ni < 4; ++ni) {
        const int col = bn * 128 + wn * 64 + ni * 16 + r16;
#pragma unroll
        for (int rr = 0; rr < 4; ++rr) {
          const int row = bm * 256 + wm * 128 + mi * 16 + g * 4 + rr;
          Qb[(size_t)row * 1024 + col] = f2bf(acc[mi][ni][rr] + bcol[ni]);
        }
      }
  } else if (bn < 10) {                      // ---- K ----
#pragma unroll
    for (int mi = 0; mi < 8; ++mi)
#pragma unroll
      for (int ni = 0; ni < 4; ++ni) {
        const int c = bn * 128 + wn * 64 + ni * 16 + r16 - 1024;
        const int gi = c >> 6, dd = c & 63;
#pragma unroll
        for (int rr = 0; rr < 4; ++rr) {
          const int row = bm * 256 + wm * 128 + mi * 16 + g * 4 + rr;
          const int bb = row >> 11, s = row & 2047;
          Kb[((size_t)(bb * 4 + gi) * 2048 + s) * 64 + dd] = f2bf(acc[mi][ni][rr] + bcol[ni]);
        }
      }
  } else {                                   // ---- V -> transposed ----
#pragma unroll
    for (int mi = 0; mi < 8; ++mi) {
      const int row0 = bm * 256 + wm * 128 + mi * 16 + g * 4;
      const int bb = row0 >> 11, s0 = row0 & 2047;
#pragma unroll
      for (int ni = 0; ni < 4; ++ni) {
        const int c = bn * 128 + wn * 64 + ni * 16 + r16 - 1280;
        const int gi = c >> 6, dd = c & 63;
        ushort4v pk;
#pragma unroll
        for (int rr = 0; rr < 4; ++rr) pk[rr] = f2bf(acc[mi][ni][rr] + bcol[ni]);
        *reinterpret_cast<ushort4v*>(Vt + ((size_t)(bb * 4 + gi) * 64 + dd) * 2048 + s0) = pk;
      }
    }
  }
}

// Output GEMM: M=8192, N=1024, K=1024, fp32 out + bias.
__global__ __launch_bounds__(256, 2) void gemm_out_kernel(
    const ushort_t* __restrict__ A, const ushort_t* __restrict__ Bt,
    const float* __restrict__ bias, float* __restrict__ Cout)
{
  __shared__ __align__(16) char LdsB[73728];
  // 256 blocks; XCD x gets bm in [x*4, x*4+4) x all 8 bn.
  const int xcd = blockIdx.x & 7, ii = blockIdx.x >> 3;   // ii in [0,32)
  const int bm = xcd * 4 + (ii >> 3), bn = ii & 7;
  GEMM_IDS
  GEMM_KLOOP(A, Bt)

  float bcol[4];
#pragma unroll
  for (int ni = 0; ni < 4; ++ni) bcol[ni] = bias[bn * 128 + wn * 64 + ni * 16 + r16];
#pragma unroll
  for (int mi = 0; mi < 8; ++mi)
#pragma unroll
    for (int ni = 0; ni < 4; ++ni) {
      const int col = bn * 128 + wn * 64 + ni * 16 + r16;
#pragma unroll
      for (int rr = 0; rr < 4; ++rr) {
        const int row = bm * 256 + wm * 128 + mi * 16 + g * 4 + rr;
        Cout[(size_t)row * 1024 + col] = acc[mi][ni][rr] + bcol[ni];
      }
    }
}

// ---------- attention (unchanged from round 4) ----------
// Block = (qtile 64, group, batch); 8 waves = 4 heads x 2 query-halves.
// KVBLK=64, double-buffered; static-max softmax; swapped QK^T.
__global__ __launch_bounds__(512, 2) void attn_kernel(
    const ushort_t* __restrict__ Qb, const ushort_t* __restrict__ Kb,
    const ushort_t* __restrict__ Vt, ushort_t* __restrict__ attout)
{
  __shared__ __align__(16) char KsB[16384];  // 2 x [64 keys][128B], swz (key&7)
  __shared__ __align__(16) char VsB[16384];  // 2 x [64 d][64 keys*2B], swz (d&7)
  const int fid = blockIdx.x + 32 * (blockIdx.y + 4 * blockIdx.z);
  const int j = fid >> 3;
  const int qt = (fid & 7) * 4 + (j >> 4);
  const int gg = j & 3, b = (j >> 2) & 3;

  const int tid = threadIdx.x;
  const int w = tid >> 6, lane = tid & 63;
  const int hw = w & 3, qh = w >> 2;
  const int h = gg * 4 + hw;
  const int g = lane >> 4, r16 = lane & 15;
  const int u0 = g >> 1;
  const int lowb = (g & 1) << 3;
  const int q0w = qt * 64 + qh * 32;

  short8 qf[2][2];
#pragma unroll
  for (int qs = 0; qs < 2; ++qs) {
    const char* qptr = (const char*)Qb + ((size_t)(b * 2048 + q0w + qs * 16 + r16) * 1024 + h * 64) * 2;
#pragma unroll
    for (int dc = 0; dc < 2; ++dc)
      qf[qs][dc] = *(const short8*)(qptr + dc * 64 + g * 16);
  }

  const f32x4 vzero = {0.f, 0.f, 0.f, 0.f};
  f32x4 accO[2][4];
#pragma unroll
  for (int qs = 0; qs < 2; ++qs)
#pragma unroll
    for (int nt = 0; nt < 4; ++nt) accO[qs][nt] = vzero;
  float lsum[2] = {0.f, 0.f};

  const char* KbB = (const char*)Kb + (size_t)(b * 4 + gg) * 2048 * 128;  // key rows 128B
  const char* VtB = (const char*)Vt + (size_t)(b * 4 + gg) * 64 * 4096;   // d rows 4096B

  const int kb0 = (qt >= 8) ? (qt * 64 - 512) : 0;
  const int NT = (qt * 64 + 64 - kb0) >> 6;

  const int srr = tid >> 3, spk = tid & 7;
  auto stage = [&](int buf, int kb) {
    gload16(KbB + (size_t)(kb + srr) * 128 + ((spk ^ (srr & 7)) << 4),
            KsB + buf * 8192 + tid * 16);
    gload16(VtB + (size_t)srr * 4096 + (size_t)kb * 2 + ((spk ^ (srr & 7)) << 4),
            VsB + buf * 8192 + tid * 16);
  };

  stage(0, kb0);
  __syncthreads();
  for (int t = 0; t < NT; ++t) {
    const int kb = kb0 + t * 64;
    const int cur = t & 1;
    if (t + 1 < NT) stage(cur ^ 1, kb + 64);
    const char* Ks = KsB + cur * 8192;
    const char* Vs = VsB + cur * 8192;
    const bool full = (kb >= q0w - 480) && (kb <= q0w - 63);

    f32x4 st[2][4];
#pragma unroll
    for (int ki = 0; ki < 4; ++ki) {
      const int key = ki * 16 + r16;
      const int swz = key & 7;
      const short8 kf0 = *(const short8*)(Ks + key * 128 + ((g ^ swz) << 4));
      const short8 kf1 = *(const short8*)(Ks + key * 128 + (((4 + g) ^ swz) << 4));
#pragma unroll
      for (int qs = 0; qs < 2; ++qs) {
        st[qs][ki] = __builtin_amdgcn_mfma_f32_16x16x32_bf16(kf0, qf[qs][0], vzero, 0, 0, 0);
        st[qs][ki] = __builtin_amdgcn_mfma_f32_16x16x32_bf16(kf1, qf[qs][1], st[qs][ki], 0, 0, 0);
      }
    }

    PFrag pf[2][2];
#pragma unroll
    for (int qs = 0; qs < 2; ++qs) {
      const int q = q0w + qs * 16 + r16;
#pragma unroll
      for (int ki = 0; ki < 4; ++ki)
#pragma unroll
        for (int r = 0; r < 4; ++r) {
          float s = st[qs][ki][r] * 0.180336881f;
          if (!full) {
            const int key = kb + ki * 16 + g * 4 + r;
            const bool valid = (key <= q) && (key + 512 > q);
            s = valid ? s : -INFINITY;
          }
          st[qs][ki][r] = __builtin_amdgcn_exp2f(s);
        }
      float tk[4];
#pragma unroll
      for (int ki = 0; ki < 4; ++ki)
        tk[ki] = (st[qs][ki][0] + st[qs][ki][1]) + (st[qs][ki][2] + st[qs][ki][3]);
      lsum[qs] += (tk[0] + tk[1]) + (tk[2] + tk[3]);
#pragma unroll
      for (int c = 0; c < 2; ++c)
#pragma unroll
        for (int pr = 0; pr < 2; ++pr) {
          asm("v_cvt_pk_bf16_f32 %0, %1, %2"
              : "=v"(pf[qs][c].w[pr * 2])
              : "v"(st[qs][2 * c + pr][0]), "v"(st[qs][2 * c + pr][1]));
          asm("v_cvt_pk_bf16_f32 %0, %1, %2"
              : "=v"(pf[qs][c].w[pr * 2 + 1])
              : "v"(st[qs][2 * c + pr][2]), "v"(st[qs][2 * c + pr][3]));
        }
    }

#pragma unroll
    for (int c = 0; c < 2; ++c)
#pragma unroll
      for (int nt = 0; nt < 4; ++nt) {
        const int d = nt * 16 + r16;
        const int swz = d & 7;
        Frag8 vf;
        vf.h[0] = *(const short4v*)(Vs + d * 128 + (((c * 4 + u0) ^ swz) << 4) + lowb);
        vf.h[1] = *(const short4v*)(Vs + d * 128 + (((c * 4 + 2 + u0) ^ swz) << 4) + lowb);
#pragma unroll
        for (int qs = 0; qs < 2; ++qs)
          accO[qs][nt] = __builtin_amdgcn_mfma_f32_16x16x32_bf16(pf[qs][c].v, vf.v, accO[qs][nt], 0, 0, 0);
      }
    __syncthreads();
  }

#pragma unroll
  for (int qs = 0; qs < 2; ++qs) {
    float ts = lsum[qs];
    ts += __shfl_xor(ts, 16);
    ts += __shfl_xor(ts, 32);
    const float linv = 1.f / ts;
    float lq[4];
#pragma unroll
    for (int rr = 0; rr < 4; ++rr) lq[rr] = __shfl(linv, g * 4 + rr);
#pragma unroll
    for (int nt = 0; nt < 4; ++nt) {
      const int ocol = h * 64 + nt * 16 + r16;
#pragma unroll
      for (int rr = 0; rr < 4; ++rr) {
        const int orow = b * 2048 + q0w + qs * 16 + g * 4 + rr;
        attout[(size_t)orow * 1024 + ocol] = f2bf(accO[qs][nt][rr] * lq[rr]);
      }
    }
  }
}

// ---------- launch ----------
extern "C" void kernel_launch(void* const* d_in, const int* in_sizes, int n_in,
                              void* d_out, int out_size, void* d_ws, size_t ws_size,
                              hipStream_t stream) {
  (void)in_sizes; (void)n_in; (void)out_size; (void)ws_size;
  const float* x  = (const float*)d_in[0];
  const float* Wq = (const float*)d_in[1];
  const float* bq = (const float*)d_in[2];
  const float* Wk = (const float*)d_in[3];
  const float* bk = (const float*)d_in[4];
  const float* Wv = (const float*)d_in[5];
  const float* bv = (const float*)d_in[6];
  const float* Wo = (const float*)d_in[7];
  const float* bo = (const float*)d_in[8];

  char* ws = (char*)d_ws;
  ushort_t* Qb   = (ushort_t*)(ws + 0);          // 8192x1024 bf16 = 16 MiB
  ushort_t* Kb   = (ushort_t*)(ws + 16777216);   // 16x2048x64 bf16 = 4 MiB
  ushort_t* Vt   = (ushort_t*)(ws + 20971520);   // 16x64x2048 bf16 = 4 MiB
  ushort_t* wt   = (ushort_t*)(ws + 25165824);   // 2560x1024 bf16 = 5 MiB
  float*    bqkv = (float*)   (ws + 30408704);   // 1536 fp32
  ushort_t* xb   = (ushort_t*)(ws + 30416896);   // 8192x1024 bf16 = 16 MiB
  ushort_t* att  = (ushort_t*)(ws + 47194112);   // 8192x1024 bf16 = 16 MiB

  cast_x_kernel<<<8192, 256, 0, stream>>>(x, xb);
  transpose_w_kernel<<<dim3(80, 32), 256, 0, stream>>>(Wq, Wk, Wv, Wo, wt);
  prep_bias_kernel<<<6, 256, 0, stream>>>(bq, bk, bv, bqkv);
  gemm_qkv_kernel<<<384, 256, 0, stream>>>(xb, wt, bqkv, Qb, Kb, Vt);
  attn_kernel<<<dim3(32, 4, 4), 512, 0, stream>>>(Qb, Kb, Vt, att);
  gemm_out_kernel<<<256, 256, 0, stream>>>(att, wt + (size_t)1536 * 1024, bo, (float*)d_out);
}

// Round 6
// 105.815 us; speedup vs baseline: 2.2155x; 1.1221x over previous
//
#include <hip/hip_runtime.h>
#include <cstdint>
#include <cstddef>

// ---------- types ----------
typedef __attribute__((ext_vector_type(8))) short short8;
typedef __attribute__((ext_vector_type(4))) short short4v;
typedef __attribute__((ext_vector_type(4))) float f32x4;
typedef __attribute__((ext_vector_type(4))) unsigned short ushort4v;
typedef unsigned short ushort_t;

union Frag8 { short4v h[2]; short8 v; };
union PFrag { unsigned int w[4]; short8 v; };

__device__ __forceinline__ ushort_t f2bf(float f) {
  unsigned int u = __builtin_bit_cast(unsigned int, f);
  u += 0x7FFFu + ((u >> 16) & 1u);   // RNE; inputs finite
  return (ushort_t)(u >> 16);
}

__device__ __forceinline__ void gload16(const void* g, void* l) {
  __builtin_amdgcn_global_load_lds(
      (const __attribute__((address_space(1))) unsigned int*)g,
      (__attribute__((address_space(3))) unsigned int*)l, 16, 0, 0);
}

// ---------- prep kernels ----------
__global__ void cast_x_kernel(const float* __restrict__ x, ushort_t* __restrict__ o) {
  int i = (blockIdx.x * 256 + threadIdx.x) * 4;
  const float4 v = *reinterpret_cast<const float4*>(x + i);
  ushort4v r = { f2bf(v.x), f2bf(v.y), f2bf(v.z), f2bf(v.w) };
  *reinterpret_cast<ushort4v*>(o + i) = r;
}

// Tiled transpose: W[k][n] fp32 -> Wt[n][k] bf16.  Wt rows: 0..1023 Wq^T,
// 1024..1279 Wk^T, 1280..1535 Wv^T, 1536..2559 Wo^T.
__global__ __launch_bounds__(256) void transpose_w_kernel(
    const float* __restrict__ Wq, const float* __restrict__ Wk,
    const float* __restrict__ Wv, const float* __restrict__ Wo,
    ushort_t* __restrict__ Wt) {
  __shared__ float tile[32][33];
  const int tn = blockIdx.x, tk = blockIdx.y;
  const int n0 = tn * 32;
  const float* W; int ldn, nloc;
  if      (n0 < 1024) { W = Wq; ldn = 1024; nloc = n0; }
  else if (n0 < 1280) { W = Wk; ldn = 256;  nloc = n0 - 1024; }
  else if (n0 < 1536) { W = Wv; ldn = 256;  nloc = n0 - 1280; }
  else                { W = Wo; ldn = 1024; nloc = n0 - 1536; }
  const int t = threadIdx.x;
  const int sr = t >> 3, sc = (t & 7) * 4;
  const float4 v = *reinterpret_cast<const float4*>(W + (size_t)(tk * 32 + sr) * ldn + nloc + sc);
  tile[sr][sc] = v.x; tile[sr][sc + 1] = v.y; tile[sr][sc + 2] = v.z; tile[sr][sc + 3] = v.w;
  __syncthreads();
  const int wr = t >> 3, wc = (t & 7) * 4;
  ushort4v o = { f2bf(tile[wc][wr]), f2bf(tile[wc + 1][wr]),
                 f2bf(tile[wc + 2][wr]), f2bf(tile[wc + 3][wr]) };
  *reinterpret_cast<ushort4v*>(Wt + (size_t)(n0 + wr) * 1024 + tk * 32 + wc) = o;
}

__global__ void prep_bias_kernel(const float* __restrict__ bq, const float* __restrict__ bk,
                                 const float* __restrict__ bv, float* __restrict__ bqkv) {
  int t = blockIdx.x * 256 + threadIdx.x;
  if (t < 1536) bqkv[t] = (t < 1024) ? bq[t] : (t < 1280) ? bk[t - 1024] : bv[t - 1280];
}

// ---------- GEMM core ----------
// Block tile 256x128, BK=32, 4 waves (2x2), per-wave 128x64 (acc[8][4]),
// 16x16x32 bf16 MFMA.  3-stage LDS pipeline, counted s_waitcnt vmcnt(6),
// raw s_barrier, setprio around the 32-MFMA cluster.
#define GEMM_IDS \
  const int tid = threadIdx.x;                        \
  const int w = tid >> 6, lane = tid & 63;            \
  const int wm = w >> 1, wn = w & 1;                  \
  const int g = lane >> 4, r16 = lane & 15;

#define GEMM_KLOOP(APTR, BPTR)                                                          \
  const f32x4 vzero = {0.f, 0.f, 0.f, 0.f};                                             \
  f32x4 acc[8][4];                                                                      \
  _Pragma("unroll") for (int i = 0; i < 8; ++i)                                         \
    _Pragma("unroll") for (int j = 0; j < 4; ++j) acc[i][j] = vzero;                    \
  const int su = (lane & 3) ^ ((lane >> 3) & 3);                                        \
  const int sr = lane >> 2;                                                             \
  auto stage = [&](int s, int k0) {                                                     \
    char* base = LdsB + s * 24576;                                                      \
    _Pragma("unroll") for (int i = 0; i < 4; ++i) {                                     \
      const int c = w * 4 + i;                                                          \
      gload16((const char*)(APTR) + (size_t)(bm * 256 + c * 16 + sr) * 2048 + k0 * 2 + su * 16, \
              base + c * 1024);                                                         \
    }                                                                                   \
    _Pragma("unroll") for (int i = 0; i < 2; ++i) {                                     \
      const int c = w * 2 + i;                                                          \
      gload16((const char*)(BPTR) + (size_t)(bn * 128 + c * 16 + sr) * 2048 + k0 * 2 + su * 16, \
              base + 16384 + c * 1024);                                                 \
    }                                                                                   \
  };                                                                                    \
  stage(0, 0);                                                                          \
  stage(1, 32);                                                                         \
  const int fsw = (g ^ ((r16 >> 1) & 3)) << 4;                                          \
  for (int t = 0; t < 32; ++t) {                                                        \
    if (t < 31) { asm volatile("s_waitcnt vmcnt(6) lgkmcnt(0)" ::: "memory"); }         \
    else        { asm volatile("s_waitcnt vmcnt(0) lgkmcnt(0)" ::: "memory"); }         \
    __builtin_amdgcn_s_barrier();                                                       \
    if (t + 2 < 32) stage((t + 2) % 3, (t + 2) * 32);                                   \
    const char* Ab = LdsB + (t % 3) * 24576;                                            \
    const char* Bb = Ab + 16384;                                                        \
    short8 af[8], bf[4];                                                                \
    _Pragma("unroll") for (int mi = 0; mi < 8; ++mi)                                    \
      af[mi] = *(const short8*)(Ab + (wm * 128 + mi * 16 + r16) * 64 + fsw);            \
    _Pragma("unroll") for (int ni = 0; ni < 4; ++ni)                                    \
      bf[ni] = *(const short8*)(Bb + (wn * 64 + ni * 16 + r16) * 64 + fsw);             \
    __builtin_amdgcn_s_setprio(1);                                                      \
    _Pragma("unroll") for (int mi = 0; mi < 8; ++mi)                                    \
      _Pragma("unroll") for (int ni = 0; ni < 4; ++ni)                                  \
        acc[mi][ni] = __builtin_amdgcn_mfma_f32_16x16x32_bf16(af[mi], bf[ni], acc[mi][ni], 0, 0, 0); \
    __builtin_amdgcn_s_setprio(0);                                                      \
  }

// QKV GEMM: M=8192, N=1536, K=1024.  Writes Qb [8192][1024] (pre-scaled by
// 0.125*log2e), Kb [b*4+g][2048][64], Vt [b*4+g][64][2048] key-permuted to
// MFMA kappa order within each 32-key chunk (pos = 8*((k>>2)&3)+(k&3)+4*((k>>4)&1)).
__global__ __launch_bounds__(256, 2) void gemm_qkv_kernel(
    const ushort_t* __restrict__ A, const ushort_t* __restrict__ Bt,
    const float* __restrict__ bias,
    ushort_t* __restrict__ Qb, ushort_t* __restrict__ Kb, ushort_t* __restrict__ Vt)
{
  __shared__ __align__(16) char LdsB[73728];
  const int xcd = blockIdx.x & 7, ii = blockIdx.x >> 3;   // ii in [0,48)
  const int bm = xcd * 4 + ii / 12, bn = ii % 12;
  GEMM_IDS
  GEMM_KLOOP(A, Bt)

  float bcol[4];
#pragma unroll
  for (int ni = 0; ni < 4; ++ni) bcol[ni] = bias[bn * 128 + wn * 64 + ni * 16 + r16];
  if (bn < 8) {                              // ---- Q (pre-scaled) ----
#pragma unroll
    for (int mi = 0; mi < 8; ++mi)
#pragma unroll
      for (int ni = 0; ni < 4; ++ni) {
        const int col = bn * 128 + wn * 64 + ni * 16 + r16;
#pragma unroll
        for (int rr = 0; rr < 4; ++rr) {
          const int row = bm * 256 + wm * 128 + mi * 16 + g * 4 + rr;
          Qb[(size_t)row * 1024 + col] = f2bf((acc[mi][ni][rr] + bcol[ni]) * 0.180336881f);
        }
      }
  } else if (bn < 10) {                      // ---- K ----
#pragma unroll
    for (int mi = 0; mi < 8; ++mi)
#pragma unroll
      for (int ni = 0; ni < 4; ++ni) {
        const int c = bn * 128 + wn * 64 + ni * 16 + r16 - 1024;
        const int gi = c >> 6, dd = c & 63;
#pragma unroll
        for (int rr = 0; rr < 4; ++rr) {
          const int row = bm * 256 + wm * 128 + mi * 16 + g * 4 + rr;
          const int bb = row >> 11, s = row & 2047;
          Kb[((size_t)(bb * 4 + gi) * 2048 + s) * 64 + dd] = f2bf(acc[mi][ni][rr] + bcol[ni]);
        }
      }
  } else {                                   // ---- V -> transposed, kappa-permuted ----
#pragma unroll
    for (int mi = 0; mi < 8; ++mi) {
      const int row0 = bm * 256 + wm * 128 + mi * 16 + g * 4;
      const int bb = row0 >> 11;
      const int s = row0 & 2047;
      const int pos = (s & ~31) + g * 8 + (mi & 1) * 4;   // kappa position of rr=0
#pragma unroll
      for (int ni = 0; ni < 4; ++ni) {
        const int c = bn * 128 + wn * 64 + ni * 16 + r16 - 1280;
        const int gi = c >> 6, dd = c & 63;
        ushort4v pk;
#pragma unroll
        for (int rr = 0; rr < 4; ++rr) pk[rr] = f2bf(acc[mi][ni][rr] + bcol[ni]);
        *reinterpret_cast<ushort4v*>(Vt + ((size_t)(bb * 4 + gi) * 64 + dd) * 2048 + pos) = pk;
      }
    }
  }
}

// Output GEMM: M=8192, N=1024, K=1024, fp32 out + bias.
__global__ __launch_bounds__(256, 2) void gemm_out_kernel(
    const ushort_t* __restrict__ A, const ushort_t* __restrict__ Bt,
    const float* __restrict__ bias, float* __restrict__ Cout)
{
  __shared__ __align__(16) char LdsB[73728];
  const int xcd = blockIdx.x & 7, ii = blockIdx.x >> 3;   // ii in [0,32)
  const int bm = xcd * 4 + (ii >> 3), bn = ii & 7;
  GEMM_IDS
  GEMM_KLOOP(A, Bt)

  float bcol[4];
#pragma unroll
  for (int ni = 0; ni < 4; ++ni) bcol[ni] = bias[bn * 128 + wn * 64 + ni * 16 + r16];
#pragma unroll
  for (int mi = 0; mi < 8; ++mi)
#pragma unroll
    for (int ni = 0; ni < 4; ++ni) {
      const int col = bn * 128 + wn * 64 + ni * 16 + r16;
#pragma unroll
      for (int rr = 0; rr < 4; ++rr) {
        const int row = bm * 256 + wm * 128 + mi * 16 + g * 4 + rr;
        Cout[(size_t)row * 1024 + col] = acc[mi][ni][rr] + bcol[ni];
      }
    }
}

// ---------- attention ----------
// Block = (qtile 64, group, batch); 8 waves = 4 heads x 2 query-halves.
// XCD-balanced map: XCD x gets ALL 32 qt (descending -> long blocks first)
// for 2 fixed (g,b) pairs (2MB KV / XCD L2).  KVBLK=64, 3-stage pipeline with
// counted vmcnt (2 stages in flight), static-max softmax with Q pre-scaled,
// mask-free fast path for interior tiles, single-b128 V fragments (kappa-
// permuted Vt).  Swapped QK^T.
__global__ __launch_bounds__(512, 2) void attn_kernel(
    const ushort_t* __restrict__ Qb, const ushort_t* __restrict__ Kb,
    const ushort_t* __restrict__ Vt, ushort_t* __restrict__ attout)
{
  __shared__ __align__(16) char KsB[24576];  // 3 x [64 keys][128B], swz (key&7)
  __shared__ __align__(16) char VsB[24576];  // 3 x [64 d][128B], swz (d&7), keys kappa-permuted
  const int fid = blockIdx.x;
  const int lo = fid & 7, hi = fid >> 3;
  const int qt = 31 - (hi & 31);
  const int gbsel = lo | ((hi >> 5) << 3);
  const int gg = gbsel & 3, b = gbsel >> 2;

  const int tid = threadIdx.x;
  const int w = tid >> 6, lane = tid & 63;
  const int hw = w & 3, qh = w >> 2;
  const int h = gg * 4 + hw;
  const int g = lane >> 4, r16 = lane & 15;
  const int q0w = qt * 64 + qh * 32;

  // Q fragments (pre-scaled): contiguous kappa, chunk dc element j -> d = dc*32+g*8+j
  short8 qf[2][2];
#pragma unroll
  for (int qs = 0; qs < 2; ++qs) {
    const char* qptr = (const char*)Qb + ((size_t)(b * 2048 + q0w + qs * 16 + r16) * 1024 + h * 64) * 2;
#pragma unroll
    for (int dc = 0; dc < 2; ++dc)
      qf[qs][dc] = *(const short8*)(qptr + dc * 64 + g * 16);
  }

  const f32x4 vzero = {0.f, 0.f, 0.f, 0.f};
  f32x4 accO[2][4];
#pragma unroll
  for (int qs = 0; qs < 2; ++qs)
#pragma unroll
    for (int nt = 0; nt < 4; ++nt) accO[qs][nt] = vzero;
  float lsum[2] = {0.f, 0.f};

  const char* KbB = (const char*)Kb + (size_t)(b * 4 + gg) * 2048 * 128;  // key rows 128B
  const char* VtB = (const char*)Vt + (size_t)(b * 4 + gg) * 64 * 4096;   // d rows 4096B

  const int kb0 = (qt >= 8) ? (qt * 64 - 512) : 0;
  const int NT = (qt * 64 + 64 - kb0) >> 6;

  const int srr = tid >> 3, spk = tid & 7;
  auto stage = [&](int buf, int kb) {
    gload16(KbB + (size_t)(kb + srr) * 128 + ((spk ^ (srr & 7)) << 4),
            KsB + buf * 8192 + tid * 16);
    gload16(VtB + (size_t)srr * 4096 + (size_t)kb * 2 + ((spk ^ (srr & 7)) << 4),
            VsB + buf * 8192 + tid * 16);
  };

  stage(0, kb0);
  if (NT > 1) stage(1, kb0 + 64);
  for (int t = 0; t < NT; ++t) {
    if (t < NT - 1) { asm volatile("s_waitcnt vmcnt(2) lgkmcnt(0)" ::: "memory"); }
    else            { asm volatile("s_waitcnt vmcnt(0) lgkmcnt(0)" ::: "memory"); }
    __builtin_amdgcn_s_barrier();
    if (t + 2 < NT) stage((t + 2) % 3, kb0 + (t + 2) * 64);
    const int kb = kb0 + t * 64;
    const char* Ks = KsB + (t % 3) * 8192;
    const char* Vs = VsB + (t % 3) * 8192;

    // QK^T: S^T tile [64 keys][32 q] per wave (scores already in exp2 domain)
    f32x4 st[2][4];
#pragma unroll
    for (int ki = 0; ki < 4; ++ki) {
      const int key = ki * 16 + r16;
      const int swz = key & 7;
      const short8 kf0 = *(const short8*)(Ks + key * 128 + ((g ^ swz) << 4));
      const short8 kf1 = *(const short8*)(Ks + key * 128 + (((4 + g) ^ swz) << 4));
#pragma unroll
      for (int qs = 0; qs < 2; ++qs) {
        st[qs][ki] = __builtin_amdgcn_mfma_f32_16x16x32_bf16(kf0, qf[qs][0], vzero, 0, 0, 0);
        st[qs][ki] = __builtin_amdgcn_mfma_f32_16x16x32_bf16(kf1, qf[qs][1], st[qs][ki], 0, 0, 0);
      }
    }

    const bool full = (kb >= q0w - 480) && (kb <= q0w - 63);   // wave-uniform
    PFrag pf[2][2];
    if (full) {
#pragma unroll
      for (int qs = 0; qs < 2; ++qs) {
#pragma unroll
        for (int ki = 0; ki < 4; ++ki)
#pragma unroll
          for (int r = 0; r < 4; ++r)
            st[qs][ki][r] = __builtin_amdgcn_exp2f(st[qs][ki][r]);
      }
    } else {
#pragma unroll
      for (int qs = 0; qs < 2; ++qs) {
        const int q = q0w + qs * 16 + r16;
#pragma unroll
        for (int ki = 0; ki < 4; ++ki)
#pragma unroll
          for (int r = 0; r < 4; ++r) {
            const int key = kb + ki * 16 + g * 4 + r;
            const bool valid = (key <= q) && (key + 512 > q);
            st[qs][ki][r] = __builtin_amdgcn_exp2f(valid ? st[qs][ki][r] : -INFINITY);
          }
      }
    }
#pragma unroll
    for (int qs = 0; qs < 2; ++qs) {
      float tk[4];
#pragma unroll
      for (int ki = 0; ki < 4; ++ki)
        tk[ki] = (st[qs][ki][0] + st[qs][ki][1]) + (st[qs][ki][2] + st[qs][ki][3]);
      lsum[qs] += (tk[0] + tk[1]) + (tk[2] + tk[3]);
#pragma unroll
      for (int c = 0; c < 2; ++c)
#pragma unroll
        for (int pr = 0; pr < 2; ++pr) {
          asm("v_cvt_pk_bf16_f32 %0, %1, %2"
              : "=v"(pf[qs][c].w[pr * 2])
              : "v"(st[qs][2 * c + pr][0]), "v"(st[qs][2 * c + pr][1]));
          asm("v_cvt_pk_bf16_f32 %0, %1, %2"
              : "=v"(pf[qs][c].w[pr * 2 + 1])
              : "v"(st[qs][2 * c + pr][2]), "v"(st[qs][2 * c + pr][3]));
        }
    }

    // PV: V fragment = single b128 (kappa-permuted keys in Vs rows)
#pragma unroll
    for (int c = 0; c < 2; ++c)
#pragma unroll
      for (int nt = 0; nt < 4; ++nt) {
        const int d = nt * 16 + r16;
        const short8 vf = *(const short8*)(Vs + d * 128 + (((c * 4 + g) ^ (d & 7)) << 4));
#pragma unroll
        for (int qs = 0; qs < 2; ++qs)
          accO[qs][nt] = __builtin_amdgcn_mfma_f32_16x16x32_bf16(pf[qs][c].v, vf, accO[qs][nt], 0, 0, 0);
      }
  }

#pragma unroll
  for (int qs = 0; qs < 2; ++qs) {
    float ts = lsum[qs];
    ts += __shfl_xor(ts, 16);
    ts += __shfl_xor(ts, 32);
    const float linv = 1.f / ts;
    float lq[4];
#pragma unroll
    for (int rr = 0; rr < 4; ++rr) lq[rr] = __shfl(linv, g * 4 + rr);
#pragma unroll
    for (int nt = 0; nt < 4; ++nt) {
      const int ocol = h * 64 + nt * 16 + r16;
#pragma unroll
      for (int rr = 0; rr < 4; ++rr) {
        const int orow = b * 2048 + q0w + qs * 16 + g * 4 + rr;
        attout[(size_t)orow * 1024 + ocol] = f2bf(accO[qs][nt][rr] * lq[rr]);
      }
    }
  }
}

// ---------- launch ----------
extern "C" void kernel_launch(void* const* d_in, const int* in_sizes, int n_in,
                              void* d_out, int out_size, void* d_ws, size_t ws_size,
                              hipStream_t stream) {
  (void)in_sizes; (void)n_in; (void)out_size; (void)ws_size;
  const float* x  = (const float*)d_in[0];
  const float* Wq = (const float*)d_in[1];
  const float* bq = (const float*)d_in[2];
  const float* Wk = (const float*)d_in[3];
  const float* bk = (const float*)d_in[4];
  const float* Wv = (const float*)d_in[5];
  const float* bv = (const float*)d_in[6];
  const float* Wo = (const float*)d_in[7];
  const float* bo = (const float*)d_in[8];

  char* ws = (char*)d_ws;
  ushort_t* Qb   = (ushort_t*)(ws + 0);          // 8192x1024 bf16 = 16 MiB
  ushort_t* Kb   = (ushort_t*)(ws + 16777216);   // 16x2048x64 bf16 = 4 MiB
  ushort_t* Vt   = (ushort_t*)(ws + 20971520);   // 16x64x2048 bf16 = 4 MiB
  ushort_t* wt   = (ushort_t*)(ws + 25165824);   // 2560x1024 bf16 = 5 MiB
  float*    bqkv = (float*)   (ws + 30408704);   // 1536 fp32
  ushort_t* xb   = (ushort_t*)(ws + 30416896);   // 8192x1024 bf16 = 16 MiB
  ushort_t* att  = (ushort_t*)(ws + 47194112);   // 8192x1024 bf16 = 16 MiB

  cast_x_kernel<<<8192, 256, 0, stream>>>(x, xb);
  transpose_w_kernel<<<dim3(80, 32), 256, 0, stream>>>(Wq, Wk, Wv, Wo, wt);
  prep_bias_kernel<<<6, 256, 0, stream>>>(bq, bk, bv, bqkv);
  gemm_qkv_kernel<<<384, 256, 0, stream>>>(xb, wt, bqkv, Qb, Kb, Vt);
  attn_kernel<<<512, 512, 0, stream>>>(Qb, Kb, Vt, att);
  gemm_out_kernel<<<256, 256, 0, stream>>>(att, wt + (size_t)1536 * 1024, bo, (float*)d_out);
}

// Round 7
// 104.047 us; speedup vs baseline: 2.2532x; 1.0170x over previous
//
#include <hip/hip_runtime.h>
#include <cstdint>
#include <cstddef>

// ---------- types ----------
typedef __attribute__((ext_vector_type(8))) short short8;
typedef __attribute__((ext_vector_type(4))) short short4v;
typedef __attribute__((ext_vector_type(4))) float f32x4;
typedef __attribute__((ext_vector_type(4))) unsigned short ushort4v;
typedef unsigned short ushort_t;

union Frag8 { short4v h[2]; short8 v; };
union PFrag { unsigned int w[4]; short8 v; };

__device__ __forceinline__ ushort_t f2bf(float f) {
  unsigned int u = __builtin_bit_cast(unsigned int, f);
  u += 0x7FFFu + ((u >> 16) & 1u);   // RNE; inputs finite
  return (ushort_t)(u >> 16);
}

__device__ __forceinline__ void gload16(const void* g, void* l) {
  __builtin_amdgcn_global_load_lds(
      (const __attribute__((address_space(1))) unsigned int*)g,
      (__attribute__((address_space(3))) unsigned int*)l, 16, 0, 0);
}

// ---------- prep kernels ----------
__global__ void cast_x_kernel(const float* __restrict__ x, ushort_t* __restrict__ o) {
  int i = (blockIdx.x * 256 + threadIdx.x) * 4;
  const float4 v = *reinterpret_cast<const float4*>(x + i);
  ushort4v r = { f2bf(v.x), f2bf(v.y), f2bf(v.z), f2bf(v.w) };
  *reinterpret_cast<ushort4v*>(o + i) = r;
}

// Tiled transpose: W[k][n] fp32 -> Wt[n][k] bf16.  Wt rows: 0..1023 Wq^T,
// 1024..1279 Wk^T, 1280..1535 Wv^T, 1536..2559 Wo^T.
__global__ __launch_bounds__(256) void transpose_w_kernel(
    const float* __restrict__ Wq, const float* __restrict__ Wk,
    const float* __restrict__ Wv, const float* __restrict__ Wo,
    ushort_t* __restrict__ Wt) {
  __shared__ float tile[32][33];
  const int tn = blockIdx.x, tk = blockIdx.y;
  const int n0 = tn * 32;
  const float* W; int ldn, nloc;
  if      (n0 < 1024) { W = Wq; ldn = 1024; nloc = n0; }
  else if (n0 < 1280) { W = Wk; ldn = 256;  nloc = n0 - 1024; }
  else if (n0 < 1536) { W = Wv; ldn = 256;  nloc = n0 - 1280; }
  else                { W = Wo; ldn = 1024; nloc = n0 - 1536; }
  const int t = threadIdx.x;
  const int sr = t >> 3, sc = (t & 7) * 4;
  const float4 v = *reinterpret_cast<const float4*>(W + (size_t)(tk * 32 + sr) * ldn + nloc + sc);
  tile[sr][sc] = v.x; tile[sr][sc + 1] = v.y; tile[sr][sc + 2] = v.z; tile[sr][sc + 3] = v.w;
  __syncthreads();
  const int wr = t >> 3, wc = (t & 7) * 4;
  ushort4v o = { f2bf(tile[wc][wr]), f2bf(tile[wc + 1][wr]),
                 f2bf(tile[wc + 2][wr]), f2bf(tile[wc + 3][wr]) };
  *reinterpret_cast<ushort4v*>(Wt + (size_t)(n0 + wr) * 1024 + tk * 32 + wc) = o;
}

__global__ void prep_bias_kernel(const float* __restrict__ bq, const float* __restrict__ bk,
                                 const float* __restrict__ bv, float* __restrict__ bqkv) {
  int t = blockIdx.x * 256 + threadIdx.x;
  if (t < 1536) bqkv[t] = (t < 1024) ? bq[t] : (t < 1280) ? bk[t - 1024] : bv[t - 1280];
}

// ---------- GEMM core ----------
// Block tile 128x128, BK=32, 4 waves (2x2), per-wave 64x64 (acc[4][4]),
// 16x16x32 bf16 MFMA.  3-stage LDS pipeline (16 KB/stage, 48 KB -> 3 blocks/CU,
// 12 waves/CU), counted s_waitcnt vmcnt(4), raw s_barrier, setprio around the
// 16-MFMA cluster.  LDS rows 64 B (4x16B units), phys unit = logical ^
// ((row>>1)&3): bank-even (8 words/bank per wave b128 read = minimum).
// Staging: linear LDS dest, pre-swizzled global source.  K=1024 (32 iters).
// Grids are exact CU multiples: 768 = 3x256 (qkv), 512 = 2x256 (out).
#define GEMM_IDS \
  const int tid = threadIdx.x;                        \
  const int w = tid >> 6, lane = tid & 63;            \
  const int wm = w >> 1, wn = w & 1;                  \
  const int g = lane >> 4, r16 = lane & 15;

#define GEMM_KLOOP(APTR, BPTR)                                                          \
  const f32x4 vzero = {0.f, 0.f, 0.f, 0.f};                                             \
  f32x4 acc[4][4];                                                                      \
  _Pragma("unroll") for (int i = 0; i < 4; ++i)                                         \
    _Pragma("unroll") for (int j = 0; j < 4; ++j) acc[i][j] = vzero;                    \
  auto stage = [&](int s, int k0) {                                                     \
    char* base = LdsB + s * 16384;                                                      \
    _Pragma("unroll") for (int i = 0; i < 2; ++i) {                                     \
      const int u = tid + i * 256;                                                      \
      const int row = u >> 2;                                                           \
      const int pu = (u & 3) ^ ((u >> 3) & 3);                                          \
      gload16((const char*)(APTR) + (size_t)(bm * 128 + row) * 2048 + k0 * 2 + pu * 16, \
              base + u * 16);                                                           \
    }                                                                                   \
    _Pragma("unroll") for (int i = 0; i < 2; ++i) {                                     \
      const int u = tid + i * 256;                                                      \
      const int row = u >> 2;                                                           \
      const int pu = (u & 3) ^ ((u >> 3) & 3);                                          \
      gload16((const char*)(BPTR) + (size_t)(bn * 128 + row) * 2048 + k0 * 2 + pu * 16, \
              base + 8192 + u * 16);                                                    \
    }                                                                                   \
  };                                                                                    \
  stage(0, 0);                                                                          \
  stage(1, 32);                                                                         \
  const int fsw = (g ^ ((r16 >> 1) & 3)) << 4;                                          \
  for (int t = 0; t < 32; ++t) {                                                        \
    if (t < 31) { asm volatile("s_waitcnt vmcnt(4) lgkmcnt(0)" ::: "memory"); }         \
    else        { asm volatile("s_waitcnt vmcnt(0) lgkmcnt(0)" ::: "memory"); }         \
    __builtin_amdgcn_s_barrier();                                                       \
    if (t + 2 < 32) stage((t + 2) % 3, (t + 2) * 32);                                   \
    const char* Ab = LdsB + (t % 3) * 16384;                                            \
    const char* Bb = Ab + 8192;                                                         \
    short8 af[4], bf[4];                                                                \
    _Pragma("unroll") for (int mi = 0; mi < 4; ++mi)                                    \
      af[mi] = *(const short8*)(Ab + (wm * 64 + mi * 16 + r16) * 64 + fsw);             \
    _Pragma("unroll") for (int ni = 0; ni < 4; ++ni)                                    \
      bf[ni] = *(const short8*)(Bb + (wn * 64 + ni * 16 + r16) * 64 + fsw);             \
    __builtin_amdgcn_s_setprio(1);                                                      \
    _Pragma("unroll") for (int mi = 0; mi < 4; ++mi)                                    \
      _Pragma("unroll") for (int ni = 0; ni < 4; ++ni)                                  \
        acc[mi][ni] = __builtin_amdgcn_mfma_f32_16x16x32_bf16(af[mi], bf[ni], acc[mi][ni], 0, 0, 0); \
    __builtin_amdgcn_s_setprio(0);                                                      \
  }

// QKV GEMM: M=8192, N=1536, K=1024.  Writes Qb [8192][1024] (pre-scaled by
// 0.125*log2e), Kb [b*4+g][2048][64], Vt [b*4+g][64][2048] key-permuted to
// MFMA kappa order within each 32-key chunk.
__global__ __launch_bounds__(256, 3) void gemm_qkv_kernel(
    const ushort_t* __restrict__ A, const ushort_t* __restrict__ Bt,
    const float* __restrict__ bias,
    ushort_t* __restrict__ Qb, ushort_t* __restrict__ Kb, ushort_t* __restrict__ Vt)
{
  __shared__ __align__(16) char LdsB[49152];
  // 768 blocks; XCD x gets bm in [x*8, x*8+8) x all 12 bn.
  const int xcd = blockIdx.x & 7, ii = blockIdx.x >> 3;   // ii in [0,96)
  const int bm = xcd * 8 + ii / 12, bn = ii % 12;
  GEMM_IDS
  GEMM_KLOOP(A, Bt)

  float bcol[4];
#pragma unroll
  for (int ni = 0; ni < 4; ++ni) bcol[ni] = bias[bn * 128 + wn * 64 + ni * 16 + r16];
  if (bn < 8) {                              // ---- Q (pre-scaled) ----
#pragma unroll
    for (int mi = 0; mi < 4; ++mi)
#pragma unroll
      for (int ni = 0; ni < 4; ++ni) {
        const int col = bn * 128 + wn * 64 + ni * 16 + r16;
#pragma unroll
        for (int rr = 0; rr < 4; ++rr) {
          const int row = bm * 128 + wm * 64 + mi * 16 + g * 4 + rr;
          Qb[(size_t)row * 1024 + col] = f2bf((acc[mi][ni][rr] + bcol[ni]) * 0.180336881f);
        }
      }
  } else if (bn < 10) {                      // ---- K ----
#pragma unroll
    for (int mi = 0; mi < 4; ++mi)
#pragma unroll
      for (int ni = 0; ni < 4; ++ni) {
        const int c = bn * 128 + wn * 64 + ni * 16 + r16 - 1024;
        const int gi = c >> 6, dd = c & 63;
#pragma unroll
        for (int rr = 0; rr < 4; ++rr) {
          const int row = bm * 128 + wm * 64 + mi * 16 + g * 4 + rr;
          const int bb = row >> 11, s = row & 2047;
          Kb[((size_t)(bb * 4 + gi) * 2048 + s) * 64 + dd] = f2bf(acc[mi][ni][rr] + bcol[ni]);
        }
      }
  } else {                                   // ---- V -> transposed, kappa-permuted ----
#pragma unroll
    for (int mi = 0; mi < 4; ++mi) {
      const int row0 = bm * 128 + wm * 64 + mi * 16 + g * 4;
      const int bb = row0 >> 11;
      const int s = row0 & 2047;
      const int pos = (s & ~31) + g * 8 + (mi & 1) * 4;   // kappa position of rr=0
#pragma unroll
      for (int ni = 0; ni < 4; ++ni) {
        const int c = bn * 128 + wn * 64 + ni * 16 + r16 - 1280;
        const int gi = c >> 6, dd = c & 63;
        ushort4v pk;
#pragma unroll
        for (int rr = 0; rr < 4; ++rr) pk[rr] = f2bf(acc[mi][ni][rr] + bcol[ni]);
        *reinterpret_cast<ushort4v*>(Vt + ((size_t)(bb * 4 + gi) * 64 + dd) * 2048 + pos) = pk;
      }
    }
  }
}

// Output GEMM: M=8192, N=1024, K=1024, fp32 out + bias.
__global__ __launch_bounds__(256, 2) void gemm_out_kernel(
    const ushort_t* __restrict__ A, const ushort_t* __restrict__ Bt,
    const float* __restrict__ bias, float* __restrict__ Cout)
{
  __shared__ __align__(16) char LdsB[49152];
  // 512 blocks; XCD x gets bm in [x*8, x*8+8) x all 8 bn.
  const int xcd = blockIdx.x & 7, ii = blockIdx.x >> 3;   // ii in [0,64)
  const int bm = xcd * 8 + (ii >> 3), bn = ii & 7;
  GEMM_IDS
  GEMM_KLOOP(A, Bt)

  float bcol[4];
#pragma unroll
  for (int ni = 0; ni < 4; ++ni) bcol[ni] = bias[bn * 128 + wn * 64 + ni * 16 + r16];
#pragma unroll
  for (int mi = 0; mi < 4; ++mi)
#pragma unroll
    for (int ni = 0; ni < 4; ++ni) {
      const int col = bn * 128 + wn * 64 + ni * 16 + r16;
#pragma unroll
      for (int rr = 0; rr < 4; ++rr) {
        const int row = bm * 128 + wm * 64 + mi * 16 + g * 4 + rr;
        Cout[(size_t)row * 1024 + col] = acc[mi][ni][rr] + bcol[ni];
      }
    }
}

// ---------- attention (unchanged from round 6) ----------
// Block = (qtile 64, group, batch); 8 waves = 4 heads x 2 query-halves.
// XCD-balanced map; KVBLK=64, 3-stage pipeline with counted vmcnt,
// static-max softmax with Q pre-scaled, mask-free fast path, single-b128
// V fragments (kappa-permuted Vt).  Swapped QK^T.
__global__ __launch_bounds__(512, 2) void attn_kernel(
    const ushort_t* __restrict__ Qb, const ushort_t* __restrict__ Kb,
    const ushort_t* __restrict__ Vt, ushort_t* __restrict__ attout)
{
  __shared__ __align__(16) char KsB[24576];  // 3 x [64 keys][128B], swz (key&7)
  __shared__ __align__(16) char VsB[24576];  // 3 x [64 d][128B], swz (d&7), keys kappa-permuted
  const int fid = blockIdx.x;
  const int lo = fid & 7, hi = fid >> 3;
  const int qt = 31 - (hi & 31);
  const int gbsel = lo | ((hi >> 5) << 3);
  const int gg = gbsel & 3, b = gbsel >> 2;

  const int tid = threadIdx.x;
  const int w = tid >> 6, lane = tid & 63;
  const int hw = w & 3, qh = w >> 2;
  const int h = gg * 4 + hw;
  const int g = lane >> 4, r16 = lane & 15;
  const int q0w = qt * 64 + qh * 32;

  short8 qf[2][2];
#pragma unroll
  for (int qs = 0; qs < 2; ++qs) {
    const char* qptr = (const char*)Qb + ((size_t)(b * 2048 + q0w + qs * 16 + r16) * 1024 + h * 64) * 2;
#pragma unroll
    for (int dc = 0; dc < 2; ++dc)
      qf[qs][dc] = *(const short8*)(qptr + dc * 64 + g * 16);
  }

  const f32x4 vzero = {0.f, 0.f, 0.f, 0.f};
  f32x4 accO[2][4];
#pragma unroll
  for (int qs = 0; qs < 2; ++qs)
#pragma unroll
    for (int nt = 0; nt < 4; ++nt) accO[qs][nt] = vzero;
  float lsum[2] = {0.f, 0.f};

  const char* KbB = (const char*)Kb + (size_t)(b * 4 + gg) * 2048 * 128;  // key rows 128B
  const char* VtB = (const char*)Vt + (size_t)(b * 4 + gg) * 64 * 4096;   // d rows 4096B

  const int kb0 = (qt >= 8) ? (qt * 64 - 512) : 0;
  const int NT = (qt * 64 + 64 - kb0) >> 6;

  const int srr = tid >> 3, spk = tid & 7;
  auto stage = [&](int buf, int kb) {
    gload16(KbB + (size_t)(kb + srr) * 128 + ((spk ^ (srr & 7)) << 4),
            KsB + buf * 8192 + tid * 16);
    gload16(VtB + (size_t)srr * 4096 + (size_t)kb * 2 + ((spk ^ (srr & 7)) << 4),
            VsB + buf * 8192 + tid * 16);
  };

  stage(0, kb0);
  if (NT > 1) stage(1, kb0 + 64);
  for (int t = 0; t < NT; ++t) {
    if (t < NT - 1) { asm volatile("s_waitcnt vmcnt(2) lgkmcnt(0)" ::: "memory"); }
    else            { asm volatile("s_waitcnt vmcnt(0) lgkmcnt(0)" ::: "memory"); }
    __builtin_amdgcn_s_barrier();
    if (t + 2 < NT) stage((t + 2) % 3, kb0 + (t + 2) * 64);
    const int kb = kb0 + t * 64;
    const char* Ks = KsB + (t % 3) * 8192;
    const char* Vs = VsB + (t % 3) * 8192;

    // QK^T: S^T tile [64 keys][32 q] per wave (scores already in exp2 domain)
    f32x4 st[2][4];
#pragma unroll
    for (int ki = 0; ki < 4; ++ki) {
      const int key = ki * 16 + r16;
      const int swz = key & 7;
      const short8 kf0 = *(const short8*)(Ks + key * 128 + ((g ^ swz) << 4));
      const short8 kf1 = *(const short8*)(Ks + key * 128 + (((4 + g) ^ swz) << 4));
#pragma unroll
      for (int qs = 0; qs < 2; ++qs) {
        st[qs][ki] = __builtin_amdgcn_mfma_f32_16x16x32_bf16(kf0, qf[qs][0], vzero, 0, 0, 0);
        st[qs][ki] = __builtin_amdgcn_mfma_f32_16x16x32_bf16(kf1, qf[qs][1], st[qs][ki], 0, 0, 0);
      }
    }

    const bool full = (kb >= q0w - 480) && (kb <= q0w - 63);   // wave-uniform
    PFrag pf[2][2];
    if (full) {
#pragma unroll
      for (int qs = 0; qs < 2; ++qs) {
#pragma unroll
        for (int ki = 0; ki < 4; ++ki)
#pragma unroll
          for (int r = 0; r < 4; ++r)
            st[qs][ki][r] = __builtin_amdgcn_exp2f(st[qs][ki][r]);
      }
    } else {
#pragma unroll
      for (int qs = 0; qs < 2; ++qs) {
        const int q = q0w + qs * 16 + r16;
#pragma unroll
        for (int ki = 0; ki < 4; ++ki)
#pragma unroll
          for (int r = 0; r < 4; ++r) {
            const int key = kb + ki * 16 + g * 4 + r;
            const bool valid = (key <= q) && (key + 512 > q);
            st[qs][ki][r] = __builtin_amdgcn_exp2f(valid ? st[qs][ki][r] : -INFINITY);
          }
      }
    }
#pragma unroll
    for (int qs = 0; qs < 2; ++qs) {
      float tk[4];
#pragma unroll
      for (int ki = 0; ki < 4; ++ki)
        tk[ki] = (st[qs][ki][0] + st[qs][ki][1]) + (st[qs][ki][2] + st[qs][ki][3]);
      lsum[qs] += (tk[0] + tk[1]) + (tk[2] + tk[3]);
#pragma unroll
      for (int c = 0; c < 2; ++c)
#pragma unroll
        for (int pr = 0; pr < 2; ++pr) {
          asm("v_cvt_pk_bf16_f32 %0, %1, %2"
              : "=v"(pf[qs][c].w[pr * 2])
              : "v"(st[qs][2 * c + pr][0]), "v"(st[qs][2 * c + pr][1]));
          asm("v_cvt_pk_bf16_f32 %0, %1, %2"
              : "=v"(pf[qs][c].w[pr * 2 + 1])
              : "v"(st[qs][2 * c + pr][2]), "v"(st[qs][2 * c + pr][3]));
        }
    }

    // PV: V fragment = single b128 (kappa-permuted keys in Vs rows)
#pragma unroll
    for (int c = 0; c < 2; ++c)
#pragma unroll
      for (int nt = 0; nt < 4; ++nt) {
        const int d = nt * 16 + r16;
        const short8 vf = *(const short8*)(Vs + d * 128 + (((c * 4 + g) ^ (d & 7)) << 4));
#pragma unroll
        for (int qs = 0; qs < 2; ++qs)
          accO[qs][nt] = __builtin_amdgcn_mfma_f32_16x16x32_bf16(pf[qs][c].v, vf, accO[qs][nt], 0, 0, 0);
      }
  }

#pragma unroll
  for (int qs = 0; qs < 2; ++qs) {
    float ts = lsum[qs];
    ts += __shfl_xor(ts, 16);
    ts += __shfl_xor(ts, 32);
    const float linv = 1.f / ts;
    float lq[4];
#pragma unroll
    for (int rr = 0; rr < 4; ++rr) lq[rr] = __shfl(linv, g * 4 + rr);
#pragma unroll
    for (int nt = 0; nt < 4; ++nt) {
      const int ocol = h * 64 + nt * 16 + r16;
#pragma unroll
      for (int rr = 0; rr < 4; ++rr) {
        const int orow = b * 2048 + q0w + qs * 16 + g * 4 + rr;
        attout[(size_t)orow * 1024 + ocol] = f2bf(accO[qs][nt][rr] * lq[rr]);
      }
    }
  }
}

// ---------- launch ----------
extern "C" void kernel_launch(void* const* d_in, const int* in_sizes, int n_in,
                              void* d_out, int out_size, void* d_ws, size_t ws_size,
                              hipStream_t stream) {
  (void)in_sizes; (void)n_in; (void)out_size; (void)ws_size;
  const float* x  = (const float*)d_in[0];
  const float* Wq = (const float*)d_in[1];
  const float* bq = (const float*)d_in[2];
  const float* Wk = (const float*)d_in[3];
  const float* bk = (const float*)d_in[4];
  const float* Wv = (const float*)d_in[5];
  const float* bv = (const float*)d_in[6];
  const float* Wo = (const float*)d_in[7];
  const float* bo = (const float*)d_in[8];

  char* ws = (char*)d_ws;
  ushort_t* Qb   = (ushort_t*)(ws + 0);          // 8192x1024 bf16 = 16 MiB
  ushort_t* Kb   = (ushort_t*)(ws + 16777216);   // 16x2048x64 bf16 = 4 MiB
  ushort_t* Vt   = (ushort_t*)(ws + 20971520);   // 16x64x2048 bf16 = 4 MiB
  ushort_t* wt   = (ushort_t*)(ws + 25165824);   // 2560x1024 bf16 = 5 MiB
  float*    bqkv = (float*)   (ws + 30408704);   // 1536 fp32
  ushort_t* xb   = (ushort_t*)(ws + 30416896);   // 8192x1024 bf16 = 16 MiB
  ushort_t* att  = (ushort_t*)(ws + 47194112);   // 8192x1024 bf16 = 16 MiB

  cast_x_kernel<<<8192, 256, 0, stream>>>(x, xb);
  transpose_w_kernel<<<dim3(80, 32), 256, 0, stream>>>(Wq, Wk, Wv, Wo, wt);
  prep_bias_kernel<<<6, 256, 0, stream>>>(bq, bk, bv, bqkv);
  gemm_qkv_kernel<<<768, 256, 0, stream>>>(xb, wt, bqkv, Qb, Kb, Vt);
  attn_kernel<<<512, 512, 0, stream>>>(Qb, Kb, Vt, att);
  gemm_out_kernel<<<512, 256, 0, stream>>>(att, wt + (size_t)1536 * 1024, bo, (float*)d_out);
}